// Round 1
// baseline (482.118 us; speedup 1.0000x reference)
//
#include <hip/hip_runtime.h>
#include <hip/hip_bf16.h>

#define N_NODES   20000
#define N_EDGES   320000
#define IN_DIM    128
#define HID       64
#define HEADS     4
#define NUM_GRAPHS 128
#define N_CLASSES 10

// ---------- dtype detection: bf16 storage read as f32 -> huge exponents ----------
__global__ void detect_kernel(const unsigned int* w, int nwords, int* flag) {
    __shared__ int s_bad;
    if (threadIdx.x == 0) s_bad = 0;
    __syncthreads();
    int bad = 0;
    for (int i = threadIdx.x; i < nwords; i += blockDim.x) {
        float v = __uint_as_float(w[i]);
        if (!(fabsf(v) <= 1e20f)) bad = 1;   // catches inf/NaN/huge
    }
    if (bad) atomicOr(&s_bad, 1);
    __syncthreads();
    if (threadIdx.x == 0) *flag = s_bad;
}

__global__ void convert_kernel(const void* in, float* out, int n, const int* flag) {
    int i = blockIdx.x * blockDim.x + threadIdx.x;
    if (i >= n) return;
    if (*flag)
        out[i] = __bfloat162float(((const __hip_bfloat16*)in)[i]);
    else
        out[i] = ((const float*)in)[i];
}

__global__ void zero_kernel(unsigned int* p, int n) {
    int i = blockIdx.x * blockDim.x + threadIdx.x;
    if (i < n) p[i] = 0u;
}

__global__ void copy_int_kernel(const int* a, int* b, int n) {
    int i = blockIdx.x * blockDim.x + threadIdx.x;
    if (i < n) b[i] = a[i];
}

// ---------- CSR build ----------
__global__ void count_kernel(const int* dst, int* cnt, int n) {
    int e = blockIdx.x * blockDim.x + threadIdx.x;
    if (e < n) atomicAdd(&cnt[dst[e]], 1);
}

__global__ void scan_kernel(const int* cnt, int* off, int n) {
    __shared__ int buf[1024];
    __shared__ int carry_s;
    int tid = threadIdx.x;
    if (tid == 0) carry_s = 0;
    __syncthreads();
    for (int base = 0; base < n; base += 1024) {
        int i = base + tid;
        int v = (i < n) ? cnt[i] : 0;
        buf[tid] = v;
        __syncthreads();
        for (int s = 1; s < 1024; s <<= 1) {
            int t = (tid >= s) ? buf[tid - s] : 0;
            __syncthreads();
            buf[tid] += t;
            __syncthreads();
        }
        int incl  = buf[tid];
        int carry = carry_s;
        if (i < n) off[i] = carry + incl - v;   // exclusive
        __syncthreads();
        if (tid == 1023) carry_s = carry + incl;
        __syncthreads();
    }
    if (tid == 0) off[n] = carry_s;
}

__global__ void fill_kernel(const int* src, const int* dst, int* off_work, int* csr_src, int n) {
    int e = blockIdx.x * blockDim.x + threadIdx.x;
    if (e >= n) return;
    int d = dst[e];
    int pos = atomicAdd(&off_work[d], 1);
    csr_src[pos] = src[e];
}

// ---------- f32 tiled GEMM: C[M,Nc] = A[M,K] @ B[K,Nc]; BM=32,BN=64,BK=32 ----------
__global__ void gemm_kernel(const float* __restrict__ A, const float* __restrict__ B,
                            float* __restrict__ C, int M, int K, int Nc) {
    __shared__ float As[32][33];   // [k][m]
    __shared__ float Bs[32][65];   // [k][n]
    int tid = threadIdx.x;
    int j  = tid & 63;
    int ty = tid >> 6;
    int bm0 = blockIdx.x * 32;
    int bn0 = blockIdx.y * 64;
    float acc[8];
#pragma unroll
    for (int i = 0; i < 8; ++i) acc[i] = 0.f;

    for (int kk = 0; kk < K; kk += 32) {
#pragma unroll
        for (int t = 0; t < 4; ++t) {            // A tile: 32x32
            int idx = tid + t * 256;
            int r = idx >> 5, c = idx & 31;
            As[c][r] = A[(bm0 + r) * K + kk + c];
        }
#pragma unroll
        for (int t = 0; t < 8; ++t) {            // B tile: 32x64
            int idx = tid + t * 256;
            int r = idx >> 6, c = idx & 63;
            Bs[r][c] = B[(kk + r) * Nc + bn0 + c];
        }
        __syncthreads();
#pragma unroll
        for (int k = 0; k < 32; ++k) {
            float b = Bs[k][j];
#pragma unroll
            for (int i = 0; i < 8; ++i)
                acc[i] += As[k][ty * 8 + i] * b;
        }
        __syncthreads();
    }
#pragma unroll
    for (int i = 0; i < 8; ++i)
        C[(bm0 + ty * 8 + i) * Nc + bn0 + j] = acc[i];
}

// ---------- per-dst online-softmax attention, H=4 D=64 (one block/dst, one wave/head) ----------
__global__ void attn_h4_kernel(const float* __restrict__ ft, const int* __restrict__ off,
                               const int* __restrict__ csr_src, float* __restrict__ out) {
    int dstv = blockIdx.x;
    int tid  = threadIdx.x;          // h = tid>>6, d = tid&63; idx == h*64+d == tid
    int idx  = dstv * 256 + tid;
    float hd = ft[idx];
    int beg = off[dstv], end = off[dstv + 1];
    float m = -3.402823e38f, l = 0.f, acc = 0.f;
    for (int e = beg; e < end; ++e) {
        int s = csr_src[e];
        float hs = ft[s * 256 + tid];
        float p = hs * hd;
#pragma unroll
        for (int o = 1; o < 64; o <<= 1) p += __shfl_xor(p, o);
        float score = p * 0.125f;                 // 1/sqrt(64)
        float mnew  = fmaxf(m, score);
        float alpha = __expf(m - mnew);
        float wgt   = __expf(score - mnew);
        l   = l * alpha + wgt;
        acc = acc * alpha + wgt * hs;
        m = mnew;
    }
    float o = (l > 0.f) ? acc / l : 0.f;
    out[idx] = fmaxf(o, 0.f);                     // relu
}

// ---------- H=1 D=64: 4 dst nodes per block (one wave each) ----------
__global__ void attn_h1_kernel(const float* __restrict__ ft, const int* __restrict__ off,
                               const int* __restrict__ csr_src, float* __restrict__ out) {
    int dstv = blockIdx.x * 4 + (threadIdx.x >> 6);
    int d    = threadIdx.x & 63;
    int idx  = dstv * 64 + d;
    float hd = ft[idx];
    int beg = off[dstv], end = off[dstv + 1];
    float m = -3.402823e38f, l = 0.f, acc = 0.f;
    for (int e = beg; e < end; ++e) {
        int s = csr_src[e];
        float hs = ft[s * 64 + d];
        float p = hs * hd;
#pragma unroll
        for (int o = 1; o < 64; o <<= 1) p += __shfl_xor(p, o);
        float score = p * 0.125f;
        float mnew  = fmaxf(m, score);
        float alpha = __expf(m - mnew);
        float wgt   = __expf(score - mnew);
        l   = l * alpha + wgt;
        acc = acc * alpha + wgt * hs;
        m = mnew;
    }
    float o = (l > 0.f) ? acc / l : 0.f;
    out[idx] = fmaxf(o, 0.f);
}

// ---------- pooling ----------
__global__ void pool_kernel(const float* __restrict__ x, const int* __restrict__ gid,
                            float* pooled, int* gcnt, int total) {
    int i = blockIdx.x * blockDim.x + threadIdx.x;
    if (i >= total) return;
    int node = i >> 6, d = i & 63;
    int g = gid[node];
    atomicAdd(&pooled[g * 64 + d], x[i]);
    if (d == 0) atomicAdd(&gcnt[g], 1);
}

// ---------- classifier: one block (64 threads) per graph ----------
__global__ void classifier_kernel(const float* __restrict__ pooled, const int* __restrict__ gcnt,
                                  const float* __restrict__ Wc, const float* __restrict__ bc,
                                  void* out, const int* flag) {
    int g = blockIdx.x;
    int d = threadIdx.x;             // 0..63
    float c = (float)max(gcnt[g], 1);
    float val = pooled[g * 64 + d] / c;
    for (int cls = 0; cls < N_CLASSES; ++cls) {
        float p = val * Wc[d * N_CLASSES + cls];
#pragma unroll
        for (int o = 1; o < 64; o <<= 1) p += __shfl_xor(p, o);
        if (d == 0) {
            float r = p + bc[cls];
            if (*flag) ((__hip_bfloat16*)out)[g * N_CLASSES + cls] = __float2bfloat16(r);
            else       ((float*)out)[g * N_CLASSES + cls] = r;
        }
    }
}

static inline size_t align256(size_t x) { return (x + 255) & ~size_t(255); }

extern "C" void kernel_launch(void* const* d_in, const int* in_sizes, int n_in,
                              void* d_out, int out_size, void* d_ws, size_t ws_size,
                              hipStream_t stream) {
    const void* h_raw  = d_in[0];
    const int*  src    = (const int*)d_in[1];
    const int*  dst    = (const int*)d_in[2];
    const int*  gid    = (const int*)d_in[3];
    const void* W1_raw = d_in[4];
    const void* W2_raw = d_in[5];
    const void* Wc_raw = d_in[6];
    const void* bc_raw = d_in[7];

    // ---- workspace layout ----
    char* w = (char*)d_ws;
    int*  flag     = (int*)w;                      w += 256;
    int*  cnt      = (int*)w;                      w += align256(N_NODES * 4);
    int*  off      = (int*)w;                      w += align256((N_NODES + 1) * 4);
    int*  off_work = (int*)w;                      w += align256(N_NODES * 4);
    int*  csr_src  = (int*)w;                      w += align256(N_EDGES * 4);
    int*  gcnt     = (int*)w;                      w += 512;   // 128 ints, contiguous with pooled
    float* pooled  = (float*)w;                    w += NUM_GRAPHS * HID * 4;  // 32768
    float* W1f     = (float*)w;                    w += align256(IN_DIM * HID * HEADS * 4);
    float* W2f     = (float*)w;                    w += align256(HID * HEADS * HID * 4);
    float* Wcf     = (float*)w;                    w += align256(HID * N_CLASSES * 4);
    float* bcf     = (float*)w;                    w += 256;
    float* h32     = (float*)w;                    w += align256((size_t)N_NODES * IN_DIM * 4);   // 10.24MB, reused as ft2
    float* ft1     = (float*)w;                    w += align256((size_t)N_NODES * 256 * 4);      // 20.48MB, reused as x2
    float* x1      = (float*)w;                    w += align256((size_t)N_NODES * 256 * 4);      // 20.48MB
    float* ft2 = h32;    // h32 dead after GEMM1
    float* x2  = ft1;    // ft1 dead after attn layer 1

    // 1) dtype detect
    hipLaunchKernelGGL(detect_kernel, dim3(1), dim3(256), 0, stream,
                       (const unsigned int*)h_raw, 4096, flag);

    // 2) convert all float tensors to f32
    {
        int n = N_NODES * IN_DIM;
        hipLaunchKernelGGL(convert_kernel, dim3((n + 255) / 256), dim3(256), 0, stream, h_raw, h32, n, flag);
        n = IN_DIM * HID * HEADS;
        hipLaunchKernelGGL(convert_kernel, dim3((n + 255) / 256), dim3(256), 0, stream, W1_raw, W1f, n, flag);
        n = HID * HEADS * HID;
        hipLaunchKernelGGL(convert_kernel, dim3((n + 255) / 256), dim3(256), 0, stream, W2_raw, W2f, n, flag);
        n = HID * N_CLASSES;
        hipLaunchKernelGGL(convert_kernel, dim3((n + 255) / 256), dim3(256), 0, stream, Wc_raw, Wcf, n, flag);
        n = N_CLASSES;
        hipLaunchKernelGGL(convert_kernel, dim3(1), dim3(256), 0, stream, bc_raw, bcf, n, flag);
    }

    // 3) CSR build (shared by both layers)
    hipLaunchKernelGGL(zero_kernel, dim3((N_NODES + 255) / 256), dim3(256), 0, stream,
                       (unsigned int*)cnt, N_NODES);
    hipLaunchKernelGGL(count_kernel, dim3((N_EDGES + 255) / 256), dim3(256), 0, stream,
                       dst, cnt, N_EDGES);
    hipLaunchKernelGGL(scan_kernel, dim3(1), dim3(1024), 0, stream, cnt, off, N_NODES);
    hipLaunchKernelGGL(copy_int_kernel, dim3((N_NODES + 255) / 256), dim3(256), 0, stream,
                       off, off_work, N_NODES);
    hipLaunchKernelGGL(fill_kernel, dim3((N_EDGES + 255) / 256), dim3(256), 0, stream,
                       src, dst, off_work, csr_src, N_EDGES);

    // 4) layer 1: ft1 = h @ W1  [20000,128]@[128,256]
    hipLaunchKernelGGL(gemm_kernel, dim3(N_NODES / 32, 256 / 64), dim3(256), 0, stream,
                       h32, W1f, ft1, N_NODES, IN_DIM, 256);
    // 5) attention layer 1 -> x1 = relu(agg) [20000,256]
    hipLaunchKernelGGL(attn_h4_kernel, dim3(N_NODES), dim3(256), 0, stream,
                       ft1, off, csr_src, x1);

    // 6) layer 2: ft2 = x1 @ W2  [20000,256]@[256,64]
    hipLaunchKernelGGL(gemm_kernel, dim3(N_NODES / 32, 1), dim3(256), 0, stream,
                       x1, W2f, ft2, N_NODES, 256, 64);
    // 7) attention layer 2 -> x2 = relu(agg) [20000,64]
    hipLaunchKernelGGL(attn_h1_kernel, dim3(N_NODES / 4), dim3(256), 0, stream,
                       ft2, off, csr_src, x2);

    // 8) mean pool per graph
    hipLaunchKernelGGL(zero_kernel, dim3((128 + NUM_GRAPHS * HID + 255) / 256), dim3(256), 0, stream,
                       (unsigned int*)gcnt, 128 + NUM_GRAPHS * HID);   // gcnt + pooled contiguous
    hipLaunchKernelGGL(pool_kernel, dim3((N_NODES * HID + 255) / 256), dim3(256), 0, stream,
                       x2, gid, pooled, gcnt, N_NODES * HID);

    // 9) classifier -> d_out
    hipLaunchKernelGGL(classifier_kernel, dim3(NUM_GRAPHS), dim3(64), 0, stream,
                       pooled, gcnt, Wcf, bcf, d_out, flag);
}

// Round 2
// 287.955 us; speedup vs baseline: 1.6743x; 1.6743x over previous
//
#include <hip/hip_runtime.h>
#include <hip/hip_bf16.h>

#define N_NODES   20000
#define N_EDGES   320000
#define IN_DIM    128
#define HID       64
#define HEADS     4
#define NUM_GRAPHS 128
#define N_CLASSES 10

// ---------- dtype detection: bf16 storage read as f32 -> huge exponents ----------
__global__ void detect_kernel(const unsigned int* w, int nwords, int* flag) {
    __shared__ int s_bad;
    if (threadIdx.x == 0) s_bad = 0;
    __syncthreads();
    int bad = 0;
    for (int i = threadIdx.x; i < nwords; i += blockDim.x) {
        float v = __uint_as_float(w[i]);
        if (!(fabsf(v) <= 1e20f)) bad = 1;
    }
    if (bad) atomicOr(&s_bad, 1);
    __syncthreads();
    if (threadIdx.x == 0) *flag = s_bad;
}

__device__ inline float cvt_load(const void* p, int i, int isb) {
    return isb ? __bfloat162float(((const __hip_bfloat16*)p)[i]) : ((const float*)p)[i];
}

// one kernel converts all four weight tensors
__global__ void convW_kernel(const void* W1, const void* W2, const void* Wc, const void* bc,
                             float* W1f, float* W2f, float* Wcf, float* bcf, const int* flag) {
    int i = blockIdx.x * 256 + threadIdx.x;
    int isb = *flag;
    const int n1 = IN_DIM * HID * HEADS;        // 32768
    const int n2 = HID * HEADS * HID;           // 16384
    const int n3 = HID * N_CLASSES;             // 640
    const int n4 = N_CLASSES;                   // 10
    if (i < n1) W1f[i] = cvt_load(W1, i, isb);
    else if (i < n1 + n2) W2f[i - n1] = cvt_load(W2, i - n1, isb);
    else if (i < n1 + n2 + n3) Wcf[i - n1 - n2] = cvt_load(Wc, i - n1 - n2, isb);
    else if (i < n1 + n2 + n3 + n4) bcf[i - n1 - n2 - n3] = cvt_load(bc, i - n1 - n2 - n3, isb);
}

// zero two regions in one launch
__global__ void zero2_kernel(unsigned int* p1, int n1, unsigned int* p2, int n2) {
    int i = blockIdx.x * blockDim.x + threadIdx.x;
    if (i < n1) p1[i] = 0u;
    int j = i - n1;
    if (j >= 0 && j < n2) p2[j] = 0u;
}

// ---------- CSR build ----------
__global__ void count_kernel(const int* dst, int* cnt, int n) {
    int e = blockIdx.x * blockDim.x + threadIdx.x;
    if (e < n) atomicAdd(&cnt[dst[e]], 1);
}

// single-block scan: wave shuffle scans, 2 barriers per 1024-chunk; writes off AND off_work
__global__ void scan_kernel(const int* cnt, int* off, int* off_work, int n) {
    __shared__ int wsum[16];
    __shared__ int carry_s;
    int tid  = threadIdx.x;
    int lane = tid & 63;
    int w    = tid >> 6;          // 16 waves
    if (tid == 0) carry_s = 0;
    __syncthreads();
    for (int base = 0; base < n; base += 1024) {
        int i = base + tid;
        int v = (i < n) ? cnt[i] : 0;
        int x = v;
#pragma unroll
        for (int s = 1; s < 64; s <<= 1) {
            int t = __shfl_up(x, s);
            if (lane >= s) x += t;
        }
        if (lane == 63) wsum[w] = x;
        __syncthreads();
        if (w == 0 && lane < 16) {
            int y = wsum[lane];
#pragma unroll
            for (int s = 1; s < 16; s <<= 1) {
                int t = __shfl_up(y, s);
                if (lane >= s) y += t;
            }
            wsum[lane] = y;
        }
        __syncthreads();
        int woff  = (w > 0) ? wsum[w - 1] : 0;
        int incl  = x + woff;
        int carry = carry_s;
        if (i < n) {
            int excl = carry + incl - v;
            off[i] = excl;
            off_work[i] = excl;
        }
        __syncthreads();
        if (tid == 1023) carry_s = carry + incl;
        __syncthreads();
    }
    if (threadIdx.x == 0) off[n] = carry_s;
}

__global__ void fill_kernel(const int* src, const int* dst, int* off_work, int* csr_src, int n) {
    int e = blockIdx.x * blockDim.x + threadIdx.x;
    if (e >= n) return;
    int d = dst[e];
    int pos = atomicAdd(&off_work[d], 1);
    csr_src[pos] = src[e];
}

// ---------- GEMM: C[M,Nc] = A[M,K] @ B[K,Nc]; 64x64 tile, 4x4 register tile ----------
// A may be bf16 (flag) -> conversion fused into staging
__global__ void gemm_kernel(const void* __restrict__ A, const float* __restrict__ B,
                            float* __restrict__ C, int M, int K, int Nc, const int* flag) {
    __shared__ float As[32][68];   // [k][m], rows 16B-aligned (68*4=272)
    __shared__ float Bs[32][68];   // [k][n]
    int isb = *flag;
    int tid = threadIdx.x;
    int tx = tid & 15, ty = tid >> 4;
    int bm0 = blockIdx.x * 64;
    int bn0 = blockIdx.y * 64;
    float acc[4][4] = {};

    for (int kk = 0; kk < K; kk += 32) {
#pragma unroll
        for (int t = 0; t < 8; ++t) {          // A tile 64x32
            int idx = tid + t * 256;
            int r = idx >> 5, c = idx & 31;
            int row = bm0 + r;
            float v = 0.f;
            if (row < M) v = cvt_load(A, row * K + kk + c, isb);
            As[c][r] = v;
        }
#pragma unroll
        for (int t = 0; t < 8; ++t) {          // B tile 32x64
            int idx = tid + t * 256;
            int r = idx >> 6, c = idx & 63;
            Bs[r][c] = B[(kk + r) * Nc + bn0 + c];
        }
        __syncthreads();
#pragma unroll
        for (int k = 0; k < 32; ++k) {
            float4 a4 = *(const float4*)&As[k][ty * 4];
            float4 b4 = *(const float4*)&Bs[k][tx * 4];
            acc[0][0] += a4.x * b4.x; acc[0][1] += a4.x * b4.y; acc[0][2] += a4.x * b4.z; acc[0][3] += a4.x * b4.w;
            acc[1][0] += a4.y * b4.x; acc[1][1] += a4.y * b4.y; acc[1][2] += a4.y * b4.z; acc[1][3] += a4.y * b4.w;
            acc[2][0] += a4.z * b4.x; acc[2][1] += a4.z * b4.y; acc[2][2] += a4.z * b4.z; acc[2][3] += a4.z * b4.w;
            acc[3][0] += a4.w * b4.x; acc[3][1] += a4.w * b4.y; acc[3][2] += a4.w * b4.z; acc[3][3] += a4.w * b4.w;
        }
        __syncthreads();
    }
#pragma unroll
    for (int i = 0; i < 4; ++i) {
        int row = bm0 + ty * 4 + i;
        if (row < M) {
            float4 o = make_float4(acc[i][0], acc[i][1], acc[i][2], acc[i][3]);
            *(float4*)&C[row * Nc + bn0 + tx * 4] = o;
        }
    }
}

// ---------- attention H=4: 1 block/dst, wave=head; 64 lanes = 4 edges x 16 dim-quads ----------
__global__ void attn_h4_kernel(const float* __restrict__ ft, const int* __restrict__ off,
                               const int* __restrict__ csr, float* __restrict__ out) {
    int dstv = blockIdx.x;
    int wave = threadIdx.x >> 6;     // head
    int lane = threadIdx.x & 63;
    int g = lane >> 4, s = lane & 15;
    int hbase = wave * 64 + s * 4;
    const float4 hd = *(const float4*)&ft[dstv * 256 + hbase];
    int beg = off[dstv], end = off[dstv + 1];
    float m = -3.0e38f, l = 0.f;
    float4 acc = make_float4(0.f, 0.f, 0.f, 0.f);

    for (int e0 = beg; e0 < end; e0 += 4) {
        int e = e0 + g;
        bool valid = (e < end);
        int sn = valid ? csr[e] : 0;
        float4 hs = make_float4(0.f, 0.f, 0.f, 0.f);
        if (valid) hs = *(const float4*)&ft[sn * 256 + hbase];
        float p = hs.x * hd.x + hs.y * hd.y + hs.z * hd.z + hs.w * hd.w;
        p += __shfl_xor(p, 1); p += __shfl_xor(p, 2);
        p += __shfl_xor(p, 4); p += __shfl_xor(p, 8);
        float score = valid ? p * 0.125f : -3.0e38f;   // 1/sqrt(64)
        float sm = score;
        sm = fmaxf(sm, __shfl_xor(sm, 16));
        sm = fmaxf(sm, __shfl_xor(sm, 32));
        float mnew  = fmaxf(m, sm);
        float alpha = __expf(m - mnew);
        float wgt   = __expf(score - mnew);
        l = l * alpha + wgt;
        acc.x = acc.x * alpha + wgt * hs.x;
        acc.y = acc.y * alpha + wgt * hs.y;
        acc.z = acc.z * alpha + wgt * hs.z;
        acc.w = acc.w * alpha + wgt * hs.w;
        m = mnew;
    }
    // merge the 4 edge-groups (shared m across wave; per-group l/acc partials)
    l += __shfl_xor(l, 16); l += __shfl_xor(l, 32);
    acc.x += __shfl_xor(acc.x, 16); acc.x += __shfl_xor(acc.x, 32);
    acc.y += __shfl_xor(acc.y, 16); acc.y += __shfl_xor(acc.y, 32);
    acc.z += __shfl_xor(acc.z, 16); acc.z += __shfl_xor(acc.z, 32);
    acc.w += __shfl_xor(acc.w, 16); acc.w += __shfl_xor(acc.w, 32);
    float inv = (l > 0.f) ? 1.f / l : 0.f;
    if (g == 0) {
        float4 o = make_float4(fmaxf(acc.x * inv, 0.f), fmaxf(acc.y * inv, 0.f),
                               fmaxf(acc.z * inv, 0.f), fmaxf(acc.w * inv, 0.f));
        *(float4*)&out[dstv * 256 + hbase] = o;
    }
}

// ---------- attention H=1: 1 wave/dst, 4 dsts/block ----------
__global__ void attn_h1_kernel(const float* __restrict__ ft, const int* __restrict__ off,
                               const int* __restrict__ csr, float* __restrict__ out) {
    int dstv = blockIdx.x * 4 + (threadIdx.x >> 6);
    int lane = threadIdx.x & 63;
    int g = lane >> 4, s = lane & 15;
    int hbase = s * 4;
    const float4 hd = *(const float4*)&ft[dstv * 64 + hbase];
    int beg = off[dstv], end = off[dstv + 1];
    float m = -3.0e38f, l = 0.f;
    float4 acc = make_float4(0.f, 0.f, 0.f, 0.f);

    for (int e0 = beg; e0 < end; e0 += 4) {
        int e = e0 + g;
        bool valid = (e < end);
        int sn = valid ? csr[e] : 0;
        float4 hs = make_float4(0.f, 0.f, 0.f, 0.f);
        if (valid) hs = *(const float4*)&ft[sn * 64 + hbase];
        float p = hs.x * hd.x + hs.y * hd.y + hs.z * hd.z + hs.w * hd.w;
        p += __shfl_xor(p, 1); p += __shfl_xor(p, 2);
        p += __shfl_xor(p, 4); p += __shfl_xor(p, 8);
        float score = valid ? p * 0.125f : -3.0e38f;
        float sm = score;
        sm = fmaxf(sm, __shfl_xor(sm, 16));
        sm = fmaxf(sm, __shfl_xor(sm, 32));
        float mnew  = fmaxf(m, sm);
        float alpha = __expf(m - mnew);
        float wgt   = __expf(score - mnew);
        l = l * alpha + wgt;
        acc.x = acc.x * alpha + wgt * hs.x;
        acc.y = acc.y * alpha + wgt * hs.y;
        acc.z = acc.z * alpha + wgt * hs.z;
        acc.w = acc.w * alpha + wgt * hs.w;
        m = mnew;
    }
    l += __shfl_xor(l, 16); l += __shfl_xor(l, 32);
    acc.x += __shfl_xor(acc.x, 16); acc.x += __shfl_xor(acc.x, 32);
    acc.y += __shfl_xor(acc.y, 16); acc.y += __shfl_xor(acc.y, 32);
    acc.z += __shfl_xor(acc.z, 16); acc.z += __shfl_xor(acc.z, 32);
    acc.w += __shfl_xor(acc.w, 16); acc.w += __shfl_xor(acc.w, 32);
    float inv = (l > 0.f) ? 1.f / l : 0.f;
    if (g == 0) {
        float4 o = make_float4(fmaxf(acc.x * inv, 0.f), fmaxf(acc.y * inv, 0.f),
                               fmaxf(acc.z * inv, 0.f), fmaxf(acc.w * inv, 0.f));
        *(float4*)&out[dstv * 64 + hbase] = o;
    }
}

// ---------- pooling: thread = (8-node chunk, dim); local accum (gids sorted) then atomic ----------
__global__ void pool_kernel(const float* __restrict__ x, const int* __restrict__ gid,
                            float* pooled, int* gcnt, int n_nodes) {
    int t = blockIdx.x * blockDim.x + threadIdx.x;
    int d = t & 63;
    int n0 = (t >> 6) * 8;
    if (n0 >= n_nodes) return;
    float accv = 0.f;
    int cnt_l = 0;
    int curg = gid[n0];
    for (int i = 0; i < 8 && n0 + i < n_nodes; ++i) {
        int g = gid[n0 + i];
        if (g != curg) {
            atomicAdd(&pooled[curg * 64 + d], accv);
            if (d == 0) atomicAdd(&gcnt[curg], cnt_l);
            accv = 0.f; cnt_l = 0; curg = g;
        }
        accv += x[(n0 + i) * 64 + d];
        cnt_l++;
    }
    atomicAdd(&pooled[curg * 64 + d], accv);
    if (d == 0) atomicAdd(&gcnt[curg], cnt_l);
}

// ---------- classifier: one block (64 threads) per graph ----------
__global__ void classifier_kernel(const float* __restrict__ pooled, const int* __restrict__ gcnt,
                                  const float* __restrict__ Wc, const float* __restrict__ bc,
                                  void* out, const int* flag) {
    int g = blockIdx.x;
    int d = threadIdx.x;
    float c = (float)max(gcnt[g], 1);
    float val = pooled[g * 64 + d] / c;
    for (int cls = 0; cls < N_CLASSES; ++cls) {
        float p = val * Wc[d * N_CLASSES + cls];
#pragma unroll
        for (int o = 1; o < 64; o <<= 1) p += __shfl_xor(p, o);
        if (d == 0) {
            float r = p + bc[cls];
            if (*flag) ((__hip_bfloat16*)out)[g * N_CLASSES + cls] = __float2bfloat16(r);
            else       ((float*)out)[g * N_CLASSES + cls] = r;
        }
    }
}

static inline size_t align256(size_t x) { return (x + 255) & ~size_t(255); }

extern "C" void kernel_launch(void* const* d_in, const int* in_sizes, int n_in,
                              void* d_out, int out_size, void* d_ws, size_t ws_size,
                              hipStream_t stream) {
    const void* h_raw  = d_in[0];
    const int*  src    = (const int*)d_in[1];
    const int*  dst    = (const int*)d_in[2];
    const int*  gid    = (const int*)d_in[3];
    const void* W1_raw = d_in[4];
    const void* W2_raw = d_in[5];
    const void* Wc_raw = d_in[6];
    const void* bc_raw = d_in[7];

    // ---- workspace layout ----
    char* w = (char*)d_ws;
    int*  flag     = (int*)w;                      w += 256;
    int*  cnt      = (int*)w;                      w += align256(N_NODES * 4);
    int*  off      = (int*)w;                      w += align256((N_NODES + 1) * 4);
    int*  off_work = (int*)w;                      w += align256(N_NODES * 4);
    int*  csr_src  = (int*)w;                      w += align256(N_EDGES * 4);
    int*  gcnt     = (int*)w;                      w += 512;   // 128 ints == 512B, contiguous w/ pooled
    float* pooled  = (float*)w;                    w += NUM_GRAPHS * HID * 4;
    float* W1f     = (float*)w;                    w += align256(IN_DIM * HID * HEADS * 4);
    float* W2f     = (float*)w;                    w += align256(HID * HEADS * HID * 4);
    float* Wcf     = (float*)w;                    w += align256(HID * N_CLASSES * 4);
    float* bcf     = (float*)w;                    w += 256;
    float* ft1     = (float*)w;                    w += align256((size_t)N_NODES * 256 * 4);   // 20.48MB
    float* x1      = (float*)w;                    w += align256((size_t)N_NODES * 256 * 4);   // 20.48MB
    float* ft2     = (float*)w;                    w += align256((size_t)N_NODES * HID * 4);   // 5.12MB
    float* x2 = ft1;   // ft1 dead after attn layer 1

    // 1) dtype detect
    hipLaunchKernelGGL(detect_kernel, dim3(1), dim3(256), 0, stream,
                       (const unsigned int*)h_raw, 4096, flag);

    // 2) weight converts (one launch) + zero cnt / gcnt+pooled (one launch)
    {
        int nW = IN_DIM * HID * HEADS + HID * HEADS * HID + HID * N_CLASSES + N_CLASSES;
        hipLaunchKernelGGL(convW_kernel, dim3((nW + 255) / 256), dim3(256), 0, stream,
                           W1_raw, W2_raw, Wc_raw, bc_raw, W1f, W2f, Wcf, bcf, flag);
        int nz = N_NODES + (128 + NUM_GRAPHS * HID);
        hipLaunchKernelGGL(zero2_kernel, dim3((nz + 255) / 256), dim3(256), 0, stream,
                           (unsigned int*)cnt, N_NODES,
                           (unsigned int*)gcnt, 128 + NUM_GRAPHS * HID);
    }

    // 3) CSR build
    hipLaunchKernelGGL(count_kernel, dim3((N_EDGES + 255) / 256), dim3(256), 0, stream,
                       dst, cnt, N_EDGES);
    hipLaunchKernelGGL(scan_kernel, dim3(1), dim3(1024), 0, stream, cnt, off, off_work, N_NODES);
    hipLaunchKernelGGL(fill_kernel, dim3((N_EDGES + 255) / 256), dim3(256), 0, stream,
                       src, dst, off_work, csr_src, N_EDGES);

    // 4) layer 1: ft1 = h @ W1  [20000,128]@[128,256]  (bf16->f32 fused into A staging)
    hipLaunchKernelGGL(gemm_kernel, dim3((N_NODES + 63) / 64, 256 / 64), dim3(256), 0, stream,
                       h_raw, W1f, ft1, N_NODES, IN_DIM, 256, flag);
    // 5) attention layer 1 -> x1
    hipLaunchKernelGGL(attn_h4_kernel, dim3(N_NODES), dim3(256), 0, stream,
                       ft1, off, csr_src, x1);

    // 6) layer 2: ft2 = x1 @ W2  [20000,256]@[256,64]  (x1 is f32; flag path reads f32 when... x1 always f32)
    // x1 is f32 — pass a flag pointer that is always 0: reuse off (off[0]==0 after scan? off[0]=0 exclusive ✓)
    hipLaunchKernelGGL(gemm_kernel, dim3((N_NODES + 63) / 64, 1), dim3(256), 0, stream,
                       x1, W2f, ft2, N_NODES, 256, 64, off /* off[0] == 0 always */);
    // 7) attention layer 2 -> x2
    hipLaunchKernelGGL(attn_h1_kernel, dim3(N_NODES / 4), dim3(256), 0, stream,
                       ft2, off, csr_src, x2);

    // 8) mean pool
    {
        int threads = (N_NODES / 8) * 64;   // 2500 chunks x 64 dims
        hipLaunchKernelGGL(pool_kernel, dim3((threads + 255) / 256), dim3(256), 0, stream,
                           x2, gid, pooled, gcnt, N_NODES);
    }

    // 9) classifier -> d_out
    hipLaunchKernelGGL(classifier_kernel, dim3(NUM_GRAPHS), dim3(64), 0, stream,
                       pooled, gcnt, Wcf, bcf, d_out, flag);
}

// Round 4
// 246.833 us; speedup vs baseline: 1.9532x; 1.1666x over previous
//
#include <hip/hip_runtime.h>
#include <hip/hip_bf16.h>

typedef __attribute__((ext_vector_type(8))) __bf16 bf16x8;
typedef __attribute__((ext_vector_type(4))) float floatx4;

#define N_NODES   20000
#define N_EDGES   320000
#define IN_DIM    128
#define HID       64
#define HEADS     4
#define NUM_GRAPHS 128
#define N_CLASSES 10

// ---------- dtype detection: bf16 storage read as f32 heuristic ----------
__global__ void detect_kernel(const unsigned int* w, int nwords, int* flag) {
    __shared__ int s_bad;
    if (threadIdx.x == 0) s_bad = 0;
    __syncthreads();
    int bad = 0;
    for (int i = threadIdx.x; i < nwords; i += blockDim.x) {
        float v = __uint_as_float(w[i]);
        if (!(fabsf(v) <= 1e20f)) bad = 1;
    }
    if (bad) atomicOr(&s_bad, 1);
    __syncthreads();
    if (threadIdx.x == 0) *flag = s_bad;
}

__device__ inline float cvt_load(const void* p, int i, int isb) {
    return isb ? __bfloat162float(((const __hip_bfloat16*)p)[i]) : ((const float*)p)[i];
}

__device__ inline unsigned short bf16bits(float v) {
    return __builtin_bit_cast(unsigned short, __float2bfloat16(v));
}

// ---------- weight prep: W1t [256][128] bf16, W2t [64][256] bf16, Wc/bc f32 ----------
__global__ void convW_kernel(const void* W1, const void* W2, const void* Wc, const void* bc,
                             unsigned short* W1t, unsigned short* W2t, float* Wcf, float* bcf,
                             const int* flag) {
    int i = blockIdx.x * 256 + threadIdx.x;
    int isb = *flag;
    const int n1 = IN_DIM * HID * HEADS;        // 32768
    const int n2 = HID * HEADS * HID;           // 16384
    const int n3 = HID * N_CLASSES;             // 640
    const int n4 = N_CLASSES;                   // 10
    if (i < n1) {
        int k = i >> 8, n = i & 255;            // W1[k][n], k<128, n<256
        W1t[n * 128 + k] = bf16bits(cvt_load(W1, i, isb));
    } else if (i < n1 + n2) {
        int j = i - n1;
        int k = j >> 6, n = j & 63;             // W2[k][n], k<256, n<64
        W2t[n * 256 + k] = bf16bits(cvt_load(W2, j, isb));
    } else if (i < n1 + n2 + n3) {
        int j = i - n1 - n2;
        Wcf[j] = cvt_load(Wc, j, isb);
    } else if (i < n1 + n2 + n3 + n4) {
        int j = i - n1 - n2 - n3;
        bcf[j] = cvt_load(bc, j, isb);
    }
}

// ---------- h -> bf16 [20000][128] ----------
__global__ void convH_kernel(const void* h, unsigned short* hb, const int* flag) {
    int i = blockIdx.x * 256 + threadIdx.x;
    if (i < N_NODES * IN_DIM) hb[i] = bf16bits(cvt_load(h, i, *flag));
}

__global__ void zero2_kernel(unsigned int* p1, int n1, unsigned int* p2, int n2) {
    int i = blockIdx.x * blockDim.x + threadIdx.x;
    if (i < n1) p1[i] = 0u;
    int j = i - n1;
    if (j >= 0 && j < n2) p2[j] = 0u;
}

// ---------- CSR build ----------
__global__ void count_kernel(const int* dst, int* cnt, int n) {
    int e = blockIdx.x * blockDim.x + threadIdx.x;
    if (e < n) atomicAdd(&cnt[dst[e]], 1);
}

__global__ void scan_kernel(const int* cnt, int* off, int* off_work, int n) {
    __shared__ int wsum[16];
    __shared__ int carry_s;
    int tid  = threadIdx.x;
    int lane = tid & 63;
    int w    = tid >> 6;
    if (tid == 0) carry_s = 0;
    __syncthreads();
    for (int base = 0; base < n; base += 1024) {
        int i = base + tid;
        int v = (i < n) ? cnt[i] : 0;
        int x = v;
#pragma unroll
        for (int s = 1; s < 64; s <<= 1) {
            int t = __shfl_up(x, s);
            if (lane >= s) x += t;
        }
        if (lane == 63) wsum[w] = x;
        __syncthreads();
        if (w == 0 && lane < 16) {
            int y = wsum[lane];
#pragma unroll
            for (int s = 1; s < 16; s <<= 1) {
                int t = __shfl_up(y, s);
                if (lane >= s) y += t;
            }
            wsum[lane] = y;
        }
        __syncthreads();
        int woff  = (w > 0) ? wsum[w - 1] : 0;
        int incl  = x + woff;
        int carry = carry_s;
        if (i < n) {
            int excl = carry + incl - v;
            off[i] = excl;
            off_work[i] = excl;
        }
        __syncthreads();
        if (tid == 1023) carry_s = carry + incl;
        __syncthreads();
    }
    if (threadIdx.x == 0) off[n] = carry_s;
}

__global__ void fill_kernel(const int* src, const int* dst, int* off_work, int* csr_src, int n) {
    int e = blockIdx.x * blockDim.x + threadIdx.x;
    if (e >= n) return;
    int d = dst[e];
    int pos = atomicAdd(&off_work[d], 1);
    csr_src[pos] = src[e];
}

// ---------- GEMM1 (MFMA): ft1[M,256] = h_b[M,128] @ W1; B pre-transposed [256][128] ----------
// No LDS: fragments loaded directly from global (B reused across blocks via L1/L2).
__global__ __launch_bounds__(256) void gemm1_kernel(const unsigned short* __restrict__ A,
                                                    const unsigned short* __restrict__ Bt,
                                                    unsigned short* __restrict__ C, int M) {
    int wave = threadIdx.x >> 6;
    int lane = threadIdx.x & 63;
    int q = lane >> 4, r = lane & 15;
    int m0 = blockIdx.x * 64;
    int n0 = wave * 64;
    floatx4 acc[4][4] = {};
    bf16x8 bfrag[4][4];
#pragma unroll
    for (int ni = 0; ni < 4; ++ni)
#pragma unroll
        for (int kk = 0; kk < 4; ++kk)
            bfrag[ni][kk] = *(const bf16x8*)(Bt + (n0 + ni * 16 + r) * 128 + kk * 32 + q * 8);
#pragma unroll
    for (int kk = 0; kk < 4; ++kk) {
        bf16x8 afrag[4];
#pragma unroll
        for (int mi = 0; mi < 4; ++mi) {
            int row = m0 + mi * 16 + r;
            bf16x8 a = {};
            if (row < M) a = *(const bf16x8*)(A + row * 128 + kk * 32 + q * 8);
            afrag[mi] = a;
        }
#pragma unroll
        for (int mi = 0; mi < 4; ++mi)
#pragma unroll
            for (int ni = 0; ni < 4; ++ni)
                acc[mi][ni] = __builtin_amdgcn_mfma_f32_16x16x32_bf16(afrag[mi], bfrag[ni][kk], acc[mi][ni], 0, 0, 0);
    }
#pragma unroll
    for (int mi = 0; mi < 4; ++mi)
#pragma unroll
        for (int rr = 0; rr < 4; ++rr) {
            int row = m0 + mi * 16 + q * 4 + rr;
            if (row < M) {
#pragma unroll
                for (int ni = 0; ni < 4; ++ni)
                    C[row * 256 + n0 + ni * 16 + r] = bf16bits(acc[mi][ni][rr]);
            }
        }
}

// ---------- GEMM2 (MFMA): ft2[M,64] = x1_b[M,256] @ W2; B pre-transposed [64][256] ----------
__global__ __launch_bounds__(256) void gemm2_kernel(const unsigned short* __restrict__ A,
                                                    const unsigned short* __restrict__ Bt,
                                                    unsigned short* __restrict__ C, int M) {
    int wave = threadIdx.x >> 6;
    int lane = threadIdx.x & 63;
    int q = lane >> 4, r = lane & 15;
    int m0 = blockIdx.x * 256 + wave * 64;
    floatx4 acc[4][4] = {};
#pragma unroll
    for (int kk = 0; kk < 8; ++kk) {
        bf16x8 bfrag[4], afrag[4];
#pragma unroll
        for (int ni = 0; ni < 4; ++ni)
            bfrag[ni] = *(const bf16x8*)(Bt + (ni * 16 + r) * 256 + kk * 32 + q * 8);
#pragma unroll
        for (int mi = 0; mi < 4; ++mi) {
            int row = m0 + mi * 16 + r;
            bf16x8 a = {};
            if (row < M) a = *(const bf16x8*)(A + row * 256 + kk * 32 + q * 8);
            afrag[mi] = a;
        }
#pragma unroll
        for (int mi = 0; mi < 4; ++mi)
#pragma unroll
            for (int ni = 0; ni < 4; ++ni)
                acc[mi][ni] = __builtin_amdgcn_mfma_f32_16x16x32_bf16(afrag[mi], bfrag[ni], acc[mi][ni], 0, 0, 0);
    }
#pragma unroll
    for (int mi = 0; mi < 4; ++mi)
#pragma unroll
        for (int rr = 0; rr < 4; ++rr) {
            int row = m0 + mi * 16 + q * 4 + rr;
            if (row < M) {
#pragma unroll
                for (int ni = 0; ni < 4; ++ni)
                    C[row * 64 + ni * 16 + r] = bf16bits(acc[mi][ni][rr]);
            }
        }
}

__device__ inline floatx4 unpack4(uint2 u) {
    floatx4 f;
    f.x = __uint_as_float(u.x << 16);
    f.y = __uint_as_float(u.x & 0xffff0000u);
    f.z = __uint_as_float(u.y << 16);
    f.w = __uint_as_float(u.y & 0xffff0000u);
    return f;
}

// ---------- attention H=4 (bf16 gather, unstable softmax): block/dst, wave=head ----------
__global__ void attn_h4_kernel(const unsigned short* __restrict__ ft, const int* __restrict__ off,
                               const int* __restrict__ csr, unsigned short* __restrict__ out) {
    int dstv = blockIdx.x;
    int wave = threadIdx.x >> 6;
    int lane = threadIdx.x & 63;
    int g = lane >> 4, s = lane & 15;
    int hbase = wave * 64 + s * 4;
    floatx4 hd = unpack4(*(const uint2*)(ft + dstv * 256 + hbase));
    int beg = off[dstv], end = off[dstv + 1];
    float l = 0.f;
    floatx4 acc = {0.f, 0.f, 0.f, 0.f};
    for (int e0 = beg; e0 < end; e0 += 4) {
        int e = e0 + g;
        bool valid = (e < end);
        int sn = valid ? csr[e] : 0;
        floatx4 hs = unpack4(*(const uint2*)(ft + sn * 256 + hbase));
        float p = hs.x * hd.x + hs.y * hd.y + hs.z * hd.z + hs.w * hd.w;
        p += __shfl_xor(p, 1); p += __shfl_xor(p, 2);
        p += __shfl_xor(p, 4); p += __shfl_xor(p, 8);
        float wgt = valid ? __expf(p * 0.125f) : 0.f;   // scores bounded: no max needed
        l += wgt;
        acc.x += wgt * hs.x; acc.y += wgt * hs.y;
        acc.z += wgt * hs.z; acc.w += wgt * hs.w;
    }
    l += __shfl_xor(l, 16); l += __shfl_xor(l, 32);
    acc.x += __shfl_xor(acc.x, 16); acc.x += __shfl_xor(acc.x, 32);
    acc.y += __shfl_xor(acc.y, 16); acc.y += __shfl_xor(acc.y, 32);
    acc.z += __shfl_xor(acc.z, 16); acc.z += __shfl_xor(acc.z, 32);
    acc.w += __shfl_xor(acc.w, 16); acc.w += __shfl_xor(acc.w, 32);
    float inv = (l > 0.f) ? 1.f / l : 0.f;
    if (g == 0) {
        uint2 o;
        o.x = (unsigned)bf16bits(fmaxf(acc.x * inv, 0.f)) |
              ((unsigned)bf16bits(fmaxf(acc.y * inv, 0.f)) << 16);
        o.y = (unsigned)bf16bits(fmaxf(acc.z * inv, 0.f)) |
              ((unsigned)bf16bits(fmaxf(acc.w * inv, 0.f)) << 16);
        *(uint2*)(out + dstv * 256 + hbase) = o;
    }
}

// ---------- attention H=1 (bf16 gather -> f32 out): 1 wave/dst, 4 dst/block ----------
__global__ void attn_h1_kernel(const unsigned short* __restrict__ ft, const int* __restrict__ off,
                               const int* __restrict__ csr, float* __restrict__ out) {
    int dstv = blockIdx.x * 4 + (threadIdx.x >> 6);
    int lane = threadIdx.x & 63;
    int g = lane >> 4, s = lane & 15;
    int hbase = s * 4;
    floatx4 hd = unpack4(*(const uint2*)(ft + dstv * 64 + hbase));
    int beg = off[dstv], end = off[dstv + 1];
    float l = 0.f;
    floatx4 acc = {0.f, 0.f, 0.f, 0.f};
    for (int e0 = beg; e0 < end; e0 += 4) {
        int e = e0 + g;
        bool valid = (e < end);
        int sn = valid ? csr[e] : 0;
        floatx4 hs = unpack4(*(const uint2*)(ft + sn * 64 + hbase));
        float p = hs.x * hd.x + hs.y * hd.y + hs.z * hd.z + hs.w * hd.w;
        p += __shfl_xor(p, 1); p += __shfl_xor(p, 2);
        p += __shfl_xor(p, 4); p += __shfl_xor(p, 8);
        float wgt = valid ? __expf(p * 0.125f) : 0.f;
        l += wgt;
        acc.x += wgt * hs.x; acc.y += wgt * hs.y;
        acc.z += wgt * hs.z; acc.w += wgt * hs.w;
    }
    l += __shfl_xor(l, 16); l += __shfl_xor(l, 32);
    acc.x += __shfl_xor(acc.x, 16); acc.x += __shfl_xor(acc.x, 32);
    acc.y += __shfl_xor(acc.y, 16); acc.y += __shfl_xor(acc.y, 32);
    acc.z += __shfl_xor(acc.z, 16); acc.z += __shfl_xor(acc.z, 32);
    acc.w += __shfl_xor(acc.w, 16); acc.w += __shfl_xor(acc.w, 32);
    float inv = (l > 0.f) ? 1.f / l : 0.f;
    if (g == 0) {
        floatx4 o = {fmaxf(acc.x * inv, 0.f), fmaxf(acc.y * inv, 0.f),
                     fmaxf(acc.z * inv, 0.f), fmaxf(acc.w * inv, 0.f)};
        *(floatx4*)(out + dstv * 64 + hbase) = o;
    }
}

// ---------- pooling ----------
__global__ void pool_kernel(const float* __restrict__ x, const int* __restrict__ gid,
                            float* pooled, int* gcnt, int n_nodes) {
    int t = blockIdx.x * blockDim.x + threadIdx.x;
    int d = t & 63;
    int n0 = (t >> 6) * 8;
    if (n0 >= n_nodes) return;
    float accv = 0.f;
    int cnt_l = 0;
    int curg = gid[n0];
    for (int i = 0; i < 8 && n0 + i < n_nodes; ++i) {
        int g = gid[n0 + i];
        if (g != curg) {
            atomicAdd(&pooled[curg * 64 + d], accv);
            if (d == 0) atomicAdd(&gcnt[curg], cnt_l);
            accv = 0.f; cnt_l = 0; curg = g;
        }
        accv += x[(n0 + i) * 64 + d];
        cnt_l++;
    }
    atomicAdd(&pooled[curg * 64 + d], accv);
    if (d == 0) atomicAdd(&gcnt[curg], cnt_l);
}

// ---------- classifier ----------
__global__ void classifier_kernel(const float* __restrict__ pooled, const int* __restrict__ gcnt,
                                  const float* __restrict__ Wc, const float* __restrict__ bc,
                                  void* out, const int* flag) {
    int g = blockIdx.x;
    int d = threadIdx.x;
    float c = (float)max(gcnt[g], 1);
    float val = pooled[g * 64 + d] / c;
    for (int cls = 0; cls < N_CLASSES; ++cls) {
        float p = val * Wc[d * N_CLASSES + cls];
#pragma unroll
        for (int o = 1; o < 64; o <<= 1) p += __shfl_xor(p, o);
        if (d == 0) {
            float r = p + bc[cls];
            if (*flag) ((__hip_bfloat16*)out)[g * N_CLASSES + cls] = __float2bfloat16(r);
            else       ((float*)out)[g * N_CLASSES + cls] = r;
        }
    }
}

static inline size_t align256(size_t x) { return (x + 255) & ~size_t(255); }

extern "C" void kernel_launch(void* const* d_in, const int* in_sizes, int n_in,
                              void* d_out, int out_size, void* d_ws, size_t ws_size,
                              hipStream_t stream) {
    const void* h_raw  = d_in[0];
    const int*  src    = (const int*)d_in[1];
    const int*  dst    = (const int*)d_in[2];
    const int*  gid    = (const int*)d_in[3];
    const void* W1_raw = d_in[4];
    const void* W2_raw = d_in[5];
    const void* Wc_raw = d_in[6];
    const void* bc_raw = d_in[7];

    // ---- workspace layout ----
    char* w = (char*)d_ws;
    int*  flag     = (int*)w;                      w += 256;
    int*  cnt      = (int*)w;                      w += align256(N_NODES * 4);
    int*  off      = (int*)w;                      w += align256((N_NODES + 1) * 4);
    int*  off_work = (int*)w;                      w += align256(N_NODES * 4);
    int*  csr_src  = (int*)w;                      w += align256(N_EDGES * 4);
    int*  gcnt     = (int*)w;                      w += 512;
    float* pooled  = (float*)w;                    w += NUM_GRAPHS * HID * 4;
    unsigned short* W1t = (unsigned short*)w;      w += align256(256 * 128 * 2);
    unsigned short* W2t = (unsigned short*)w;      w += align256(64 * 256 * 2);
    float* Wcf     = (float*)w;                    w += align256(HID * N_CLASSES * 4);
    float* bcf     = (float*)w;                    w += 256;
    unsigned short* h_b  = (unsigned short*)w;     w += align256((size_t)N_NODES * IN_DIM * 2);  // 5.12MB
    unsigned short* ft1  = (unsigned short*)w;     w += align256((size_t)N_NODES * 256 * 2);     // 10.24MB
    unsigned short* x1   = (unsigned short*)w;     w += align256((size_t)N_NODES * 256 * 2);     // 10.24MB
    unsigned short* ft2  = (unsigned short*)w;     w += align256((size_t)N_NODES * HID * 2);     // 2.56MB
    float* x2      = (float*)w;                    w += align256((size_t)N_NODES * HID * 4);     // 5.12MB

    // 1) dtype detect
    hipLaunchKernelGGL(detect_kernel, dim3(1), dim3(256), 0, stream,
                       (const unsigned int*)h_raw, 4096, flag);

    // 2) prep: weights (transpose->bf16), h->bf16, zero cnt/gcnt/pooled
    {
        int nW = IN_DIM * HID * HEADS + HID * HEADS * HID + HID * N_CLASSES + N_CLASSES;
        hipLaunchKernelGGL(convW_kernel, dim3((nW + 255) / 256), dim3(256), 0, stream,
                           W1_raw, W2_raw, Wc_raw, bc_raw, W1t, W2t, Wcf, bcf, flag);
        hipLaunchKernelGGL(convH_kernel, dim3((N_NODES * IN_DIM + 255) / 256), dim3(256), 0, stream,
                           h_raw, h_b, flag);
        int nz = N_NODES + (128 + NUM_GRAPHS * HID);
        hipLaunchKernelGGL(zero2_kernel, dim3((nz + 255) / 256), dim3(256), 0, stream,
                           (unsigned int*)cnt, N_NODES,
                           (unsigned int*)gcnt, 128 + NUM_GRAPHS * HID);
    }

    // 3) CSR build
    hipLaunchKernelGGL(count_kernel, dim3((N_EDGES + 255) / 256), dim3(256), 0, stream,
                       dst, cnt, N_EDGES);
    hipLaunchKernelGGL(scan_kernel, dim3(1), dim3(1024), 0, stream, cnt, off, off_work, N_NODES);
    hipLaunchKernelGGL(fill_kernel, dim3((N_EDGES + 255) / 256), dim3(256), 0, stream,
                       src, dst, off_work, csr_src, N_EDGES);

    // 4) layer 1 GEMM (MFMA): ft1 = h_b @ W1
    hipLaunchKernelGGL(gemm1_kernel, dim3((N_NODES + 63) / 64), dim3(256), 0, stream,
                       h_b, W1t, ft1, N_NODES);
    // 5) attention layer 1 -> x1 (bf16)
    hipLaunchKernelGGL(attn_h4_kernel, dim3(N_NODES), dim3(256), 0, stream,
                       ft1, off, csr_src, x1);

    // 6) layer 2 GEMM (MFMA): ft2 = x1 @ W2
    hipLaunchKernelGGL(gemm2_kernel, dim3((N_NODES + 255) / 256), dim3(256), 0, stream,
                       x1, W2t, ft2, N_NODES);
    // 7) attention layer 2 -> x2 (f32)
    hipLaunchKernelGGL(attn_h1_kernel, dim3(N_NODES / 4), dim3(256), 0, stream,
                       ft2, off, csr_src, x2);

    // 8) mean pool
    {
        int threads = (N_NODES / 8) * 64;
        hipLaunchKernelGGL(pool_kernel, dim3((threads + 255) / 256), dim3(256), 0, stream,
                           x2, gid, pooled, gcnt, N_NODES);
    }

    // 9) classifier -> d_out
    hipLaunchKernelGGL(classifier_kernel, dim3(NUM_GRAPHS), dim3(64), 0, stream,
                       pooled, gcnt, Wcf, bcf, d_out, flag);
}

// Round 6
// 243.944 us; speedup vs baseline: 1.9763x; 1.0118x over previous
//
#include <hip/hip_runtime.h>
#include <hip/hip_bf16.h>

typedef __attribute__((ext_vector_type(8))) __bf16 bf16x8;
typedef __attribute__((ext_vector_type(4))) float floatx4;

#define N_NODES   20000
#define N_EDGES   320000
#define IN_DIM    128
#define HID       64
#define HEADS     4
#define NUM_GRAPHS 128
#define N_CLASSES 10

// ---------- dtype detection: bf16 storage read as f32 heuristic ----------
__global__ void detect_kernel(const unsigned int* w, int nwords, int* flag) {
    __shared__ int s_bad;
    if (threadIdx.x == 0) s_bad = 0;
    __syncthreads();
    int bad = 0;
    for (int i = threadIdx.x; i < nwords; i += blockDim.x) {
        float v = __uint_as_float(w[i]);
        if (!(fabsf(v) <= 1e20f)) bad = 1;
    }
    if (bad) atomicOr(&s_bad, 1);
    __syncthreads();
    if (threadIdx.x == 0) *flag = s_bad;
}

__device__ inline float cvt_load(const void* p, int i, int isb) {
    return isb ? __bfloat162float(((const __hip_bfloat16*)p)[i]) : ((const float*)p)[i];
}

__device__ inline unsigned short bf16bits(float v) {
    return __builtin_bit_cast(unsigned short, __float2bfloat16(v));
}

__device__ inline unsigned pack2(float a, float b) {
    return (unsigned)bf16bits(a) | ((unsigned)bf16bits(b) << 16);
}

// ---------- weight prep: W1t [256][128] bf16, W2t [64][256] bf16, Wc/bc f32 ----------
__global__ void convW_kernel(const void* W1, const void* W2, const void* Wc, const void* bc,
                             unsigned short* W1t, unsigned short* W2t, float* Wcf, float* bcf,
                             const int* flag) {
    int i = blockIdx.x * 256 + threadIdx.x;
    int isb = *flag;
    const int n1 = IN_DIM * HID * HEADS;        // 32768
    const int n2 = HID * HEADS * HID;           // 16384
    const int n3 = HID * N_CLASSES;             // 640
    const int n4 = N_CLASSES;                   // 10
    if (i < n1) {
        int k = i >> 8, n = i & 255;            // W1[k][n], k<128, n<256
        W1t[n * 128 + k] = bf16bits(cvt_load(W1, i, isb));
    } else if (i < n1 + n2) {
        int j = i - n1;
        int k = j >> 6, n = j & 63;             // W2[k][n], k<256, n<64
        W2t[n * 256 + k] = bf16bits(cvt_load(W2, j, isb));
    } else if (i < n1 + n2 + n3) {
        int j = i - n1 - n2;
        Wcf[j] = cvt_load(Wc, j, isb);
    } else if (i < n1 + n2 + n3 + n4) {
        int j = i - n1 - n2 - n3;
        bcf[j] = cvt_load(bc, j, isb);
    }
}

// ---------- h -> bf16 [20000][128] ----------
__global__ void convH_kernel(const void* h, unsigned short* hb, const int* flag) {
    int i = blockIdx.x * 256 + threadIdx.x;
    if (i < N_NODES * IN_DIM) hb[i] = bf16bits(cvt_load(h, i, *flag));
}

__global__ void zero2_kernel(unsigned int* p1, int n1, unsigned int* p2, int n2) {
    int i = blockIdx.x * blockDim.x + threadIdx.x;
    if (i < n1) p1[i] = 0u;
    int j = i - n1;
    if (j >= 0 && j < n2) p2[j] = 0u;
}

// ---------- CSR build ----------
__global__ void count_kernel(const int* dst, int* cnt, int n) {
    int e = blockIdx.x * blockDim.x + threadIdx.x;
    if (e < n) atomicAdd(&cnt[dst[e]], 1);
}

__global__ void scan_kernel(const int* cnt, int* off, int* off_work, int n) {
    __shared__ int wsum[16];
    __shared__ int carry_s;
    int tid  = threadIdx.x;
    int lane = tid & 63;
    int w    = tid >> 6;
    if (tid == 0) carry_s = 0;
    __syncthreads();
    for (int base = 0; base < n; base += 1024) {
        int i = base + tid;
        int v = (i < n) ? cnt[i] : 0;
        int x = v;
#pragma unroll
        for (int s = 1; s < 64; s <<= 1) {
            int t = __shfl_up(x, s);
            if (lane >= s) x += t;
        }
        if (lane == 63) wsum[w] = x;
        __syncthreads();
        if (w == 0 && lane < 16) {
            int y = wsum[lane];
#pragma unroll
            for (int s = 1; s < 16; s <<= 1) {
                int t = __shfl_up(y, s);
                if (lane >= s) y += t;
            }
            wsum[lane] = y;
        }
        __syncthreads();
        int woff  = (w > 0) ? wsum[w - 1] : 0;
        int incl  = x + woff;
        int carry = carry_s;
        if (i < n) {
            int excl = carry + incl - v;
            off[i] = excl;
            off_work[i] = excl;
        }
        __syncthreads();
        if (tid == 1023) carry_s = carry + incl;
        __syncthreads();
    }
    if (threadIdx.x == 0) off[n] = carry_s;
}

__global__ void fill_kernel(const int* src, const int* dst, int* off_work, int* csr_src, int n) {
    int e = blockIdx.x * blockDim.x + threadIdx.x;
    if (e >= n) return;
    int d = dst[e];
    int pos = atomicAdd(&off_work[d], 1);
    csr_src[pos] = src[e];
}

// ---------- GEMM1 (MFMA): ft1[M,256] = h_b[M,128] @ W1; B pre-transposed [256][128] ----------
__global__ __launch_bounds__(256) void gemm1_kernel(const unsigned short* __restrict__ A,
                                                    const unsigned short* __restrict__ Bt,
                                                    unsigned short* __restrict__ C, int M) {
    int wave = threadIdx.x >> 6;
    int lane = threadIdx.x & 63;
    int q = lane >> 4, r = lane & 15;
    int m0 = blockIdx.x * 64;
    int n0 = wave * 64;
    floatx4 acc[4][4] = {};
    bf16x8 bfrag[4][4];
#pragma unroll
    for (int ni = 0; ni < 4; ++ni)
#pragma unroll
        for (int kk = 0; kk < 4; ++kk)
            bfrag[ni][kk] = *(const bf16x8*)(Bt + (n0 + ni * 16 + r) * 128 + kk * 32 + q * 8);
#pragma unroll
    for (int kk = 0; kk < 4; ++kk) {
        bf16x8 afrag[4];
#pragma unroll
        for (int mi = 0; mi < 4; ++mi) {
            int row = m0 + mi * 16 + r;
            bf16x8 a = {};
            if (row < M) a = *(const bf16x8*)(A + row * 128 + kk * 32 + q * 8);
            afrag[mi] = a;
        }
#pragma unroll
        for (int mi = 0; mi < 4; ++mi)
#pragma unroll
            for (int ni = 0; ni < 4; ++ni)
                acc[mi][ni] = __builtin_amdgcn_mfma_f32_16x16x32_bf16(afrag[mi], bfrag[ni][kk], acc[mi][ni], 0, 0, 0);
    }
#pragma unroll
    for (int mi = 0; mi < 4; ++mi)
#pragma unroll
        for (int rr = 0; rr < 4; ++rr) {
            int row = m0 + mi * 16 + q * 4 + rr;
            if (row < M) {
#pragma unroll
                for (int ni = 0; ni < 4; ++ni)
                    C[row * 256 + n0 + ni * 16 + r] = bf16bits(acc[mi][ni][rr]);
            }
        }
}

// ---------- GEMM2 (MFMA): ft2[M,64] = x1_b[M,256] @ W2; B pre-transposed [64][256] ----------
__global__ __launch_bounds__(256) void gemm2_kernel(const unsigned short* __restrict__ A,
                                                    const unsigned short* __restrict__ Bt,
                                                    unsigned short* __restrict__ C, int M) {
    int wave = threadIdx.x >> 6;
    int lane = threadIdx.x & 63;
    int q = lane >> 4, r = lane & 15;
    int m0 = blockIdx.x * 256 + wave * 64;
    floatx4 acc[4][4] = {};
#pragma unroll
    for (int kk = 0; kk < 8; ++kk) {
        bf16x8 bfrag[4], afrag[4];
#pragma unroll
        for (int ni = 0; ni < 4; ++ni)
            bfrag[ni] = *(const bf16x8*)(Bt + (ni * 16 + r) * 256 + kk * 32 + q * 8);
#pragma unroll
        for (int mi = 0; mi < 4; ++mi) {
            int row = m0 + mi * 16 + r;
            bf16x8 a = {};
            if (row < M) a = *(const bf16x8*)(A + row * 256 + kk * 32 + q * 8);
            afrag[mi] = a;
        }
#pragma unroll
        for (int mi = 0; mi < 4; ++mi)
#pragma unroll
            for (int ni = 0; ni < 4; ++ni)
                acc[mi][ni] = __builtin_amdgcn_mfma_f32_16x16x32_bf16(afrag[mi], bfrag[ni], acc[mi][ni], 0, 0, 0);
    }
#pragma unroll
    for (int mi = 0; mi < 4; ++mi)
#pragma unroll
        for (int rr = 0; rr < 4; ++rr) {
            int row = m0 + mi * 16 + q * 4 + rr;
            if (row < M) {
#pragma unroll
                for (int ni = 0; ni < 4; ++ni)
                    C[row * 64 + ni * 16 + r] = bf16bits(acc[mi][ni][rr]);
            }
        }
}

__device__ inline floatx4 unpack4(uint2 u) {
    floatx4 f;
    f.x = __uint_as_float(u.x << 16);
    f.y = __uint_as_float(u.x & 0xffff0000u);
    f.z = __uint_as_float(u.y << 16);
    f.w = __uint_as_float(u.y & 0xffff0000u);
    return f;
}

// ---------- attention H=4: ONE WAVE = ONE DST, all 4 heads (THE ONE CHANGE THIS ROUND) ----------
// 64 lanes = full 256-dim row (4 dims/lane). Head h = lanes [16h,16h+16): xor-1/2/4/8
// reduces exactly within a head group. No merge epilogue. Plain csr[e] scalar load.
__global__ __launch_bounds__(256) void attn_h4_kernel(const unsigned short* __restrict__ ft,
                                                      const int* __restrict__ off,
                                                      const int* __restrict__ csr,
                                                      unsigned short* __restrict__ out) {
    int dstv = blockIdx.x * 4 + (threadIdx.x >> 6);
    int lane = threadIdx.x & 63;
    floatx4 hd = unpack4(*(const uint2*)(ft + dstv * 256 + lane * 4));
    int beg = off[dstv], end = off[dstv + 1];
    float l = 0.f;
    floatx4 acc = {0.f, 0.f, 0.f, 0.f};
    for (int e = beg; e < end; ++e) {
        int sn = csr[e];
        floatx4 hs = unpack4(*(const uint2*)(ft + sn * 256 + lane * 4));
        float p = hs.x * hd.x + hs.y * hd.y + hs.z * hd.z + hs.w * hd.w;
        p += __shfl_xor(p, 1); p += __shfl_xor(p, 2);
        p += __shfl_xor(p, 4); p += __shfl_xor(p, 8);
        float wgt = __expf(p * 0.125f);   // |score| bounded -> unstable softmax exact
        l += wgt;
        acc.x += wgt * hs.x; acc.y += wgt * hs.y;
        acc.z += wgt * hs.z; acc.w += wgt * hs.w;
    }
    float inv = (l > 0.f) ? 1.f / l : 0.f;
    uint2 o;
    o.x = pack2(fmaxf(acc.x * inv, 0.f), fmaxf(acc.y * inv, 0.f));
    o.y = pack2(fmaxf(acc.z * inv, 0.f), fmaxf(acc.w * inv, 0.f));
    *(uint2*)(out + dstv * 256 + lane * 4) = o;
}

// ---------- attention H=1 (R4-proven): wave = dst, 4 edge-groups x 16 lanes ----------
__global__ __launch_bounds__(256) void attn_h1_kernel(const unsigned short* __restrict__ ft,
                                                      const int* __restrict__ off,
                                                      const int* __restrict__ csr,
                                                      float* __restrict__ out) {
    int dstv = blockIdx.x * 4 + (threadIdx.x >> 6);
    int lane = threadIdx.x & 63;
    int g = lane >> 4, s = lane & 15;
    int hbase = s * 4;
    floatx4 hd = unpack4(*(const uint2*)(ft + dstv * 64 + hbase));
    int beg = off[dstv], end = off[dstv + 1];
    float l = 0.f;
    floatx4 acc = {0.f, 0.f, 0.f, 0.f};
    for (int e0 = beg; e0 < end; e0 += 4) {
        int e = e0 + g;
        bool valid = (e < end);
        int sn = valid ? csr[e] : 0;
        floatx4 hs = unpack4(*(const uint2*)(ft + sn * 64 + hbase));
        float p = hs.x * hd.x + hs.y * hd.y + hs.z * hd.z + hs.w * hd.w;
        p += __shfl_xor(p, 1); p += __shfl_xor(p, 2);
        p += __shfl_xor(p, 4); p += __shfl_xor(p, 8);
        float wgt = valid ? __expf(p * 0.125f) : 0.f;
        l += wgt;
        acc.x += wgt * hs.x; acc.y += wgt * hs.y;
        acc.z += wgt * hs.z; acc.w += wgt * hs.w;
    }
    l += __shfl_xor(l, 16); l += __shfl_xor(l, 32);
    acc.x += __shfl_xor(acc.x, 16); acc.x += __shfl_xor(acc.x, 32);
    acc.y += __shfl_xor(acc.y, 16); acc.y += __shfl_xor(acc.y, 32);
    acc.z += __shfl_xor(acc.z, 16); acc.z += __shfl_xor(acc.z, 32);
    acc.w += __shfl_xor(acc.w, 16); acc.w += __shfl_xor(acc.w, 32);
    float inv = (l > 0.f) ? 1.f / l : 0.f;
    if (g == 0) {
        floatx4 o = {fmaxf(acc.x * inv, 0.f), fmaxf(acc.y * inv, 0.f),
                     fmaxf(acc.z * inv, 0.f), fmaxf(acc.w * inv, 0.f)};
        *(floatx4*)(out + dstv * 64 + hbase) = o;
    }
}

// ---------- pooling (R4-proven) ----------
__global__ void pool_kernel(const float* __restrict__ x, const int* __restrict__ gid,
                            float* pooled, int* gcnt, int n_nodes) {
    int t = blockIdx.x * blockDim.x + threadIdx.x;
    int d = t & 63;
    int n0 = (t >> 6) * 8;
    if (n0 >= n_nodes) return;
    float accv = 0.f;
    int cnt_l = 0;
    int curg = gid[n0];
    for (int i = 0; i < 8 && n0 + i < n_nodes; ++i) {
        int g = gid[n0 + i];
        if (g != curg) {
            atomicAdd(&pooled[curg * 64 + d], accv);
            if (d == 0) atomicAdd(&gcnt[curg], cnt_l);
            accv = 0.f; cnt_l = 0; curg = g;
        }
        accv += x[(n0 + i) * 64 + d];
        cnt_l++;
    }
    atomicAdd(&pooled[curg * 64 + d], accv);
    if (d == 0) atomicAdd(&gcnt[curg], cnt_l);
}

// ---------- classifier (R4-proven) ----------
__global__ void classifier_kernel(const float* __restrict__ pooled, const int* __restrict__ gcnt,
                                  const float* __restrict__ Wc, const float* __restrict__ bc,
                                  void* out, const int* flag) {
    int g = blockIdx.x;
    int d = threadIdx.x;
    float c = (float)max(gcnt[g], 1);
    float val = pooled[g * 64 + d] / c;
    for (int cls = 0; cls < N_CLASSES; ++cls) {
        float p = val * Wc[d * N_CLASSES + cls];
#pragma unroll
        for (int o = 1; o < 64; o <<= 1) p += __shfl_xor(p, o);
        if (d == 0) {
            float r = p + bc[cls];
            if (*flag) ((__hip_bfloat16*)out)[g * N_CLASSES + cls] = __float2bfloat16(r);
            else       ((float*)out)[g * N_CLASSES + cls] = r;
        }
    }
}

static inline size_t align256(size_t x) { return (x + 255) & ~size_t(255); }

extern "C" void kernel_launch(void* const* d_in, const int* in_sizes, int n_in,
                              void* d_out, int out_size, void* d_ws, size_t ws_size,
                              hipStream_t stream) {
    const void* h_raw  = d_in[0];
    const int*  src    = (const int*)d_in[1];
    const int*  dst    = (const int*)d_in[2];
    const int*  gid    = (const int*)d_in[3];
    const void* W1_raw = d_in[4];
    const void* W2_raw = d_in[5];
    const void* Wc_raw = d_in[6];
    const void* bc_raw = d_in[7];

    // ---- workspace layout (R4) ----
    char* w = (char*)d_ws;
    int*  flag     = (int*)w;                      w += 256;
    int*  cnt      = (int*)w;                      w += align256(N_NODES * 4);
    int*  off      = (int*)w;                      w += align256((N_NODES + 1) * 4);
    int*  off_work = (int*)w;                      w += align256(N_NODES * 4);
    int*  csr_src  = (int*)w;                      w += align256(N_EDGES * 4);
    int*  gcnt     = (int*)w;                      w += 512;
    float* pooled  = (float*)w;                    w += NUM_GRAPHS * HID * 4;
    unsigned short* W1t = (unsigned short*)w;      w += align256(256 * 128 * 2);
    unsigned short* W2t = (unsigned short*)w;      w += align256(64 * 256 * 2);
    float* Wcf     = (float*)w;                    w += align256(HID * N_CLASSES * 4);
    float* bcf     = (float*)w;                    w += 256;
    unsigned short* h_b  = (unsigned short*)w;     w += align256((size_t)N_NODES * IN_DIM * 2);
    unsigned short* ft1  = (unsigned short*)w;     w += align256((size_t)N_NODES * 256 * 2);
    unsigned short* x1   = (unsigned short*)w;     w += align256((size_t)N_NODES * 256 * 2);
    unsigned short* ft2  = (unsigned short*)w;     w += align256((size_t)N_NODES * HID * 2);
    float* x2      = (float*)w;                    w += align256((size_t)N_NODES * HID * 4);

    // 1) dtype detect
    hipLaunchKernelGGL(detect_kernel, dim3(1), dim3(256), 0, stream,
                       (const unsigned int*)h_raw, 4096, flag);

    // 2) prep: weights (transpose->bf16), h->bf16, zero cnt/gcnt/pooled
    {
        int nW = IN_DIM * HID * HEADS + HID * HEADS * HID + HID * N_CLASSES + N_CLASSES;
        hipLaunchKernelGGL(convW_kernel, dim3((nW + 255) / 256), dim3(256), 0, stream,
                           W1_raw, W2_raw, Wc_raw, bc_raw, W1t, W2t, Wcf, bcf, flag);
        hipLaunchKernelGGL(convH_kernel, dim3((N_NODES * IN_DIM + 255) / 256), dim3(256), 0, stream,
                           h_raw, h_b, flag);
        int nz = N_NODES + (128 + NUM_GRAPHS * HID);
        hipLaunchKernelGGL(zero2_kernel, dim3((nz + 255) / 256), dim3(256), 0, stream,
                           (unsigned int*)cnt, N_NODES,
                           (unsigned int*)gcnt, 128 + NUM_GRAPHS * HID);
    }

    // 3) CSR build
    hipLaunchKernelGGL(count_kernel, dim3((N_EDGES + 255) / 256), dim3(256), 0, stream,
                       dst, cnt, N_EDGES);
    hipLaunchKernelGGL(scan_kernel, dim3(1), dim3(1024), 0, stream, cnt, off, off_work, N_NODES);
    hipLaunchKernelGGL(fill_kernel, dim3((N_EDGES + 255) / 256), dim3(256), 0, stream,
                       src, dst, off_work, csr_src, N_EDGES);

    // 4) layer 1 GEMM (MFMA): ft1 = h_b @ W1
    hipLaunchKernelGGL(gemm1_kernel, dim3((N_NODES + 63) / 64), dim3(256), 0, stream,
                       h_b, W1t, ft1, N_NODES);
    // 5) attention layer 1 -> x1 (bf16)  [NEW: wave-per-dst, grid N/4]
    hipLaunchKernelGGL(attn_h4_kernel, dim3(N_NODES / 4), dim3(256), 0, stream,
                       ft1, off, csr_src, x1);

    // 6) layer 2 GEMM (MFMA): ft2 = x1 @ W2
    hipLaunchKernelGGL(gemm2_kernel, dim3((N_NODES + 255) / 256), dim3(256), 0, stream,
                       x1, W2t, ft2, N_NODES);
    // 7) attention layer 2 -> x2 (f32)
    hipLaunchKernelGGL(attn_h1_kernel, dim3(N_NODES / 4), dim3(256), 0, stream,
                       ft2, off, csr_src, x2);

    // 8) mean pool
    {
        int threads = (N_NODES / 8) * 64;
        hipLaunchKernelGGL(pool_kernel, dim3((threads + 255) / 256), dim3(256), 0, stream,
                           x2, gid, pooled, gcnt, N_NODES);
    }

    // 9) classifier -> d_out
    hipLaunchKernelGGL(classifier_kernel, dim3(NUM_GRAPHS), dim3(64), 0, stream,
                       pooled, gcnt, Wcf, bcf, d_out, flag);
}

// Round 7
// 221.111 us; speedup vs baseline: 2.1804x; 1.1033x over previous
//
#include <hip/hip_runtime.h>
#include <hip/hip_bf16.h>

typedef __attribute__((ext_vector_type(8))) __bf16 bf16x8;
typedef __attribute__((ext_vector_type(4))) float floatx4;

#define N_NODES   20000
#define N_EDGES   320000
#define IN_DIM    128
#define HID       64
#define HEADS     4
#define NUM_GRAPHS 128
#define N_CLASSES 10

__device__ inline float cvt_load(const void* p, int i, int isb) {
    return isb ? __bfloat162float(((const __hip_bfloat16*)p)[i]) : ((const float*)p)[i];
}

__device__ inline unsigned short bf16bits(float v) {
    return __builtin_bit_cast(unsigned short, __float2bfloat16(v));
}

__device__ inline unsigned pack2(float a, float b) {
    return (unsigned)bf16bits(a) | ((unsigned)bf16bits(b) << 16);
}

__device__ inline floatx4 unpack4(uint2 u) {
    floatx4 f;
    f.x = __uint_as_float(u.x << 16);
    f.y = __uint_as_float(u.x & 0xffff0000u);
    f.z = __uint_as_float(u.y << 16);
    f.w = __uint_as_float(u.y & 0xffff0000u);
    return f;
}

// ---------- init: block 0 = dtype detect; remaining blocks zero cnt and gcnt+pooled ----------
__global__ void init_kernel(const unsigned int* hw, int nwords, int* flag,
                            unsigned int* cnt, int n1, unsigned int* gz, int n2) {
    int b = blockIdx.x;
    if (b == 0) {
        __shared__ int s_bad;
        if (threadIdx.x == 0) s_bad = 0;
        __syncthreads();
        int bad = 0;
        for (int i = threadIdx.x; i < nwords; i += 256) {
            float v = __uint_as_float(hw[i]);
            if (!(fabsf(v) <= 1e20f)) bad = 1;
        }
        if (bad) atomicOr(&s_bad, 1);
        __syncthreads();
        if (threadIdx.x == 0) *flag = s_bad;
    } else {
        int i = (b - 1) * 256 + threadIdx.x;
        if (i < n1) cnt[i] = 0u;
        int j = i - n1;
        if (j >= 0 && j < n2) gz[j] = 0u;
    }
}

// ---------- fused prep: convW [0,195) | convH [195,10195) | count [10195,11445) ----------
__global__ void prep_kernel(const void* W1, const void* W2, const void* Wc, const void* bc,
                            unsigned short* W1t, unsigned short* W2t, float* Wcf, float* bcf,
                            const void* h, unsigned short* hb,
                            const int* __restrict__ dst, int* __restrict__ cnt,
                            const int* flag) {
    int b = blockIdx.x;
    const int n1 = IN_DIM * HID * HEADS;        // 32768
    const int n2 = HID * HEADS * HID;           // 16384
    const int n3 = HID * N_CLASSES;             // 640
    const int n4 = N_CLASSES;                   // 10
    if (b < 195) {
        int i = b * 256 + threadIdx.x;
        int isb = *flag;
        if (i < n1) {
            int k = i >> 8, n = i & 255;            // W1[k][n]
            W1t[n * 128 + k] = bf16bits(cvt_load(W1, i, isb));
        } else if (i < n1 + n2) {
            int j = i - n1;
            int k = j >> 6, n = j & 63;             // W2[k][n]
            W2t[n * 256 + k] = bf16bits(cvt_load(W2, j, isb));
        } else if (i < n1 + n2 + n3) {
            int j = i - n1 - n2;
            Wcf[j] = cvt_load(Wc, j, isb);
        } else if (i < n1 + n2 + n3 + n4) {
            int j = i - n1 - n2 - n3;
            bcf[j] = cvt_load(bc, j, isb);
        }
    } else if (b < 195 + 10000) {
        int i = (b - 195) * 256 + threadIdx.x;
        int isb = *flag;
        if (i < N_NODES * IN_DIM) hb[i] = bf16bits(cvt_load(h, i, isb));
    } else {
        int e = (b - 10195) * 256 + threadIdx.x;
        if (e < N_EDGES) atomicAdd(&cnt[dst[e]], 1);
    }
}

// ---------- scan (R6-proven) ----------
__global__ void scan_kernel(const int* cnt, int* off, int* off_work, int n) {
    __shared__ int wsum[16];
    __shared__ int carry_s;
    int tid  = threadIdx.x;
    int lane = tid & 63;
    int w    = tid >> 6;
    if (tid == 0) carry_s = 0;
    __syncthreads();
    for (int base = 0; base < n; base += 1024) {
        int i = base + tid;
        int v = (i < n) ? cnt[i] : 0;
        int x = v;
#pragma unroll
        for (int s = 1; s < 64; s <<= 1) {
            int t = __shfl_up(x, s);
            if (lane >= s) x += t;
        }
        if (lane == 63) wsum[w] = x;
        __syncthreads();
        if (w == 0 && lane < 16) {
            int y = wsum[lane];
#pragma unroll
            for (int s = 1; s < 16; s <<= 1) {
                int t = __shfl_up(y, s);
                if (lane >= s) y += t;
            }
            wsum[lane] = y;
        }
        __syncthreads();
        int woff  = (w > 0) ? wsum[w - 1] : 0;
        int incl  = x + woff;
        int carry = carry_s;
        if (i < n) {
            int excl = carry + incl - v;
            off[i] = excl;
            off_work[i] = excl;
        }
        __syncthreads();
        if (tid == 1023) carry_s = carry + incl;
        __syncthreads();
    }
    if (threadIdx.x == 0) off[n] = carry_s;
}

__global__ void fill_kernel(const int* src, const int* dst, int* off_work, int* csr_src, int n) {
    int e = blockIdx.x * blockDim.x + threadIdx.x;
    if (e >= n) return;
    int d = dst[e];
    int pos = atomicAdd(&off_work[d], 1);
    csr_src[pos] = src[e];
}

// ---------- GEMM1 (MFMA, R6-proven): ft1[M,256] = h_b[M,128] @ W1 ----------
__global__ __launch_bounds__(256) void gemm1_kernel(const unsigned short* __restrict__ A,
                                                    const unsigned short* __restrict__ Bt,
                                                    unsigned short* __restrict__ C, int M) {
    int wave = threadIdx.x >> 6;
    int lane = threadIdx.x & 63;
    int q = lane >> 4, r = lane & 15;
    int m0 = blockIdx.x * 64;
    int n0 = wave * 64;
    floatx4 acc[4][4] = {};
    bf16x8 bfrag[4][4];
#pragma unroll
    for (int ni = 0; ni < 4; ++ni)
#pragma unroll
        for (int kk = 0; kk < 4; ++kk)
            bfrag[ni][kk] = *(const bf16x8*)(Bt + (n0 + ni * 16 + r) * 128 + kk * 32 + q * 8);
#pragma unroll
    for (int kk = 0; kk < 4; ++kk) {
        bf16x8 afrag[4];
#pragma unroll
        for (int mi = 0; mi < 4; ++mi) {
            int row = m0 + mi * 16 + r;
            bf16x8 a = {};
            if (row < M) a = *(const bf16x8*)(A + row * 128 + kk * 32 + q * 8);
            afrag[mi] = a;
        }
#pragma unroll
        for (int mi = 0; mi < 4; ++mi)
#pragma unroll
            for (int ni = 0; ni < 4; ++ni)
                acc[mi][ni] = __builtin_amdgcn_mfma_f32_16x16x32_bf16(afrag[mi], bfrag[ni][kk], acc[mi][ni], 0, 0, 0);
    }
#pragma unroll
    for (int mi = 0; mi < 4; ++mi)
#pragma unroll
        for (int rr = 0; rr < 4; ++rr) {
            int row = m0 + mi * 16 + q * 4 + rr;
            if (row < M) {
#pragma unroll
                for (int ni = 0; ni < 4; ++ni)
                    C[row * 256 + n0 + ni * 16 + r] = bf16bits(acc[mi][ni][rr]);
            }
        }
}

// ---------- GEMM2 (MFMA, R6-proven): ft2[M,64] = x1_b[M,256] @ W2 ----------
__global__ __launch_bounds__(256) void gemm2_kernel(const unsigned short* __restrict__ A,
                                                    const unsigned short* __restrict__ Bt,
                                                    unsigned short* __restrict__ C, int M) {
    int wave = threadIdx.x >> 6;
    int lane = threadIdx.x & 63;
    int q = lane >> 4, r = lane & 15;
    int m0 = blockIdx.x * 256 + wave * 64;
    floatx4 acc[4][4] = {};
#pragma unroll
    for (int kk = 0; kk < 8; ++kk) {
        bf16x8 bfrag[4], afrag[4];
#pragma unroll
        for (int ni = 0; ni < 4; ++ni)
            bfrag[ni] = *(const bf16x8*)(Bt + (ni * 16 + r) * 256 + kk * 32 + q * 8);
#pragma unroll
        for (int mi = 0; mi < 4; ++mi) {
            int row = m0 + mi * 16 + r;
            bf16x8 a = {};
            if (row < M) a = *(const bf16x8*)(A + row * 256 + kk * 32 + q * 8);
            afrag[mi] = a;
        }
#pragma unroll
        for (int mi = 0; mi < 4; ++mi)
#pragma unroll
            for (int ni = 0; ni < 4; ++ni)
                acc[mi][ni] = __builtin_amdgcn_mfma_f32_16x16x32_bf16(afrag[mi], bfrag[ni], acc[mi][ni], 0, 0, 0);
    }
#pragma unroll
    for (int mi = 0; mi < 4; ++mi)
#pragma unroll
        for (int rr = 0; rr < 4; ++rr) {
            int row = m0 + mi * 16 + q * 4 + rr;
            if (row < M) {
#pragma unroll
                for (int ni = 0; ni < 4; ++ni)
                    C[row * 64 + ni * 16 + r] = bf16bits(acc[mi][ni][rr]);
            }
        }
}

// ---------- attention H=4: wave = dst, all 4 heads; UNROLL-BY-2 (this round's change) ----------
__global__ __launch_bounds__(256) void attn_h4_kernel(const unsigned short* __restrict__ ft,
                                                      const int* __restrict__ off,
                                                      const int* __restrict__ csr,
                                                      unsigned short* __restrict__ out) {
    int dstv = blockIdx.x * 4 + (threadIdx.x >> 6);
    int lane = threadIdx.x & 63;
    floatx4 hd = unpack4(*(const uint2*)(ft + dstv * 256 + lane * 4));
    int beg = off[dstv], end = off[dstv + 1];
    float l = 0.f;
    floatx4 acc = {0.f, 0.f, 0.f, 0.f};
    int e = beg;
    for (; e + 2 <= end; e += 2) {
        int sn0 = csr[e];
        int sn1 = csr[e + 1];
        uint2 r0 = *(const uint2*)(ft + sn0 * 256 + lane * 4);
        uint2 r1 = *(const uint2*)(ft + sn1 * 256 + lane * 4);
        floatx4 h0 = unpack4(r0);
        floatx4 h1 = unpack4(r1);
        float p0 = h0.x * hd.x + h0.y * hd.y + h0.z * hd.z + h0.w * hd.w;
        float p1 = h1.x * hd.x + h1.y * hd.y + h1.z * hd.z + h1.w * hd.w;
        p0 += __shfl_xor(p0, 1); p1 += __shfl_xor(p1, 1);
        p0 += __shfl_xor(p0, 2); p1 += __shfl_xor(p1, 2);
        p0 += __shfl_xor(p0, 4); p1 += __shfl_xor(p1, 4);
        p0 += __shfl_xor(p0, 8); p1 += __shfl_xor(p1, 8);
        float w0 = __expf(p0 * 0.125f);
        float w1 = __expf(p1 * 0.125f);
        l += w0 + w1;
        acc.x += w0 * h0.x + w1 * h1.x;
        acc.y += w0 * h0.y + w1 * h1.y;
        acc.z += w0 * h0.z + w1 * h1.z;
        acc.w += w0 * h0.w + w1 * h1.w;
    }
    if (e < end) {
        int sn = csr[e];
        floatx4 hs = unpack4(*(const uint2*)(ft + sn * 256 + lane * 4));
        float p = hs.x * hd.x + hs.y * hd.y + hs.z * hd.z + hs.w * hd.w;
        p += __shfl_xor(p, 1); p += __shfl_xor(p, 2);
        p += __shfl_xor(p, 4); p += __shfl_xor(p, 8);
        float wgt = __expf(p * 0.125f);
        l += wgt;
        acc.x += wgt * hs.x; acc.y += wgt * hs.y;
        acc.z += wgt * hs.z; acc.w += wgt * hs.w;
    }
    float inv = (l > 0.f) ? 1.f / l : 0.f;
    uint2 o;
    o.x = pack2(fmaxf(acc.x * inv, 0.f), fmaxf(acc.y * inv, 0.f));
    o.y = pack2(fmaxf(acc.z * inv, 0.f), fmaxf(acc.w * inv, 0.f));
    *(uint2*)(out + dstv * 256 + lane * 4) = o;
}

// ---------- attention H=1 (R6-proven): wave = dst, 4 edge-groups x 16 lanes ----------
__global__ __launch_bounds__(256) void attn_h1_kernel(const unsigned short* __restrict__ ft,
                                                      const int* __restrict__ off,
                                                      const int* __restrict__ csr,
                                                      float* __restrict__ out) {
    int dstv = blockIdx.x * 4 + (threadIdx.x >> 6);
    int lane = threadIdx.x & 63;
    int g = lane >> 4, s = lane & 15;
    int hbase = s * 4;
    floatx4 hd = unpack4(*(const uint2*)(ft + dstv * 64 + hbase));
    int beg = off[dstv], end = off[dstv + 1];
    float l = 0.f;
    floatx4 acc = {0.f, 0.f, 0.f, 0.f};
    for (int e0 = beg; e0 < end; e0 += 4) {
        int e = e0 + g;
        bool valid = (e < end);
        int sn = valid ? csr[e] : 0;
        floatx4 hs = unpack4(*(const uint2*)(ft + sn * 64 + hbase));
        float p = hs.x * hd.x + hs.y * hd.y + hs.z * hd.z + hs.w * hd.w;
        p += __shfl_xor(p, 1); p += __shfl_xor(p, 2);
        p += __shfl_xor(p, 4); p += __shfl_xor(p, 8);
        float wgt = valid ? __expf(p * 0.125f) : 0.f;
        l += wgt;
        acc.x += wgt * hs.x; acc.y += wgt * hs.y;
        acc.z += wgt * hs.z; acc.w += wgt * hs.w;
    }
    l += __shfl_xor(l, 16); l += __shfl_xor(l, 32);
    acc.x += __shfl_xor(acc.x, 16); acc.x += __shfl_xor(acc.x, 32);
    acc.y += __shfl_xor(acc.y, 16); acc.y += __shfl_xor(acc.y, 32);
    acc.z += __shfl_xor(acc.z, 16); acc.z += __shfl_xor(acc.z, 32);
    acc.w += __shfl_xor(acc.w, 16); acc.w += __shfl_xor(acc.w, 32);
    float inv = (l > 0.f) ? 1.f / l : 0.f;
    if (g == 0) {
        floatx4 o = {fmaxf(acc.x * inv, 0.f), fmaxf(acc.y * inv, 0.f),
                     fmaxf(acc.z * inv, 0.f), fmaxf(acc.w * inv, 0.f)};
        *(floatx4*)(out + dstv * 64 + hbase) = o;
    }
}

// ---------- pooling (R6-proven) ----------
__global__ void pool_kernel(const float* __restrict__ x, const int* __restrict__ gid,
                            float* pooled, int* gcnt, int n_nodes) {
    int t = blockIdx.x * blockDim.x + threadIdx.x;
    int d = t & 63;
    int n0 = (t >> 6) * 8;
    if (n0 >= n_nodes) return;
    float accv = 0.f;
    int cnt_l = 0;
    int curg = gid[n0];
    for (int i = 0; i < 8 && n0 + i < n_nodes; ++i) {
        int g = gid[n0 + i];
        if (g != curg) {
            atomicAdd(&pooled[curg * 64 + d], accv);
            if (d == 0) atomicAdd(&gcnt[curg], cnt_l);
            accv = 0.f; cnt_l = 0; curg = g;
        }
        accv += x[(n0 + i) * 64 + d];
        cnt_l++;
    }
    atomicAdd(&pooled[curg * 64 + d], accv);
    if (d == 0) atomicAdd(&gcnt[curg], cnt_l);
}

// ---------- classifier (R6-proven) ----------
__global__ void classifier_kernel(const float* __restrict__ pooled, const int* __restrict__ gcnt,
                                  const float* __restrict__ Wc, const float* __restrict__ bc,
                                  void* out, const int* flag) {
    int g = blockIdx.x;
    int d = threadIdx.x;
    float c = (float)max(gcnt[g], 1);
    float val = pooled[g * 64 + d] / c;
    for (int cls = 0; cls < N_CLASSES; ++cls) {
        float p = val * Wc[d * N_CLASSES + cls];
#pragma unroll
        for (int o = 1; o < 64; o <<= 1) p += __shfl_xor(p, o);
        if (d == 0) {
            float r = p + bc[cls];
            if (*flag) ((__hip_bfloat16*)out)[g * N_CLASSES + cls] = __float2bfloat16(r);
            else       ((float*)out)[g * N_CLASSES + cls] = r;
        }
    }
}

static inline size_t align256(size_t x) { return (x + 255) & ~size_t(255); }

extern "C" void kernel_launch(void* const* d_in, const int* in_sizes, int n_in,
                              void* d_out, int out_size, void* d_ws, size_t ws_size,
                              hipStream_t stream) {
    const void* h_raw  = d_in[0];
    const int*  src    = (const int*)d_in[1];
    const int*  dst    = (const int*)d_in[2];
    const int*  gid    = (const int*)d_in[3];
    const void* W1_raw = d_in[4];
    const void* W2_raw = d_in[5];
    const void* Wc_raw = d_in[6];
    const void* bc_raw = d_in[7];

    // ---- workspace layout (R6) ----
    char* w = (char*)d_ws;
    int*  flag     = (int*)w;                      w += 256;
    int*  cnt      = (int*)w;                      w += align256(N_NODES * 4);
    int*  off      = (int*)w;                      w += align256((N_NODES + 1) * 4);
    int*  off_work = (int*)w;                      w += align256(N_NODES * 4);
    int*  csr_src  = (int*)w;                      w += align256(N_EDGES * 4);
    int*  gcnt     = (int*)w;                      w += 512;
    float* pooled  = (float*)w;                    w += NUM_GRAPHS * HID * 4;
    unsigned short* W1t = (unsigned short*)w;      w += align256(256 * 128 * 2);
    unsigned short* W2t = (unsigned short*)w;      w += align256(64 * 256 * 2);
    float* Wcf     = (float*)w;                    w += align256(HID * N_CLASSES * 4);
    float* bcf     = (float*)w;                    w += 256;
    unsigned short* h_b  = (unsigned short*)w;     w += align256((size_t)N_NODES * IN_DIM * 2);
    unsigned short* ft1  = (unsigned short*)w;     w += align256((size_t)N_NODES * 256 * 2);
    unsigned short* x1   = (unsigned short*)w;     w += align256((size_t)N_NODES * 256 * 2);
    unsigned short* ft2  = (unsigned short*)w;     w += align256((size_t)N_NODES * HID * 2);
    float* x2      = (float*)w;                    w += align256((size_t)N_NODES * HID * 4);

    // 1) init: detect (block 0) + zero cnt/gcnt/pooled
    {
        int nz = N_NODES + (128 + NUM_GRAPHS * HID);      // 28320
        hipLaunchKernelGGL(init_kernel, dim3(1 + (nz + 255) / 256), dim3(256), 0, stream,
                           (const unsigned int*)h_raw, 4096, flag,
                           (unsigned int*)cnt, N_NODES,
                           (unsigned int*)gcnt, 128 + NUM_GRAPHS * HID);
    }

    // 2) fused prep: convW (195) + convH (10000) + count (1250)
    hipLaunchKernelGGL(prep_kernel, dim3(195 + 10000 + 1250), dim3(256), 0, stream,
                       W1_raw, W2_raw, Wc_raw, bc_raw, W1t, W2t, Wcf, bcf,
                       h_raw, h_b, dst, cnt, flag);

    // 3) CSR scan + fill
    hipLaunchKernelGGL(scan_kernel, dim3(1), dim3(1024), 0, stream, cnt, off, off_work, N_NODES);
    hipLaunchKernelGGL(fill_kernel, dim3((N_EDGES + 255) / 256), dim3(256), 0, stream,
                       src, dst, off_work, csr_src, N_EDGES);

    // 4) layer 1 GEMM (MFMA)
    hipLaunchKernelGGL(gemm1_kernel, dim3((N_NODES + 63) / 64), dim3(256), 0, stream,
                       h_b, W1t, ft1, N_NODES);
    // 5) attention layer 1 -> x1 (bf16)
    hipLaunchKernelGGL(attn_h4_kernel, dim3(N_NODES / 4), dim3(256), 0, stream,
                       ft1, off, csr_src, x1);

    // 6) layer 2 GEMM (MFMA)
    hipLaunchKernelGGL(gemm2_kernel, dim3((N_NODES + 255) / 256), dim3(256), 0, stream,
                       x1, W2t, ft2, N_NODES);
    // 7) attention layer 2 -> x2 (f32)
    hipLaunchKernelGGL(attn_h1_kernel, dim3(N_NODES / 4), dim3(256), 0, stream,
                       ft2, off, csr_src, x2);

    // 8) mean pool
    {
        int threads = (N_NODES / 8) * 64;
        hipLaunchKernelGGL(pool_kernel, dim3((threads + 255) / 256), dim3(256), 0, stream,
                           x2, gid, pooled, gcnt, N_NODES);
    }

    // 9) classifier -> d_out
    hipLaunchKernelGGL(classifier_kernel, dim3(NUM_GRAPHS), dim3(64), 0, stream,
                       pooled, gcnt, Wcf, bcf, d_out, flag);
}

// Round 8
// 217.242 us; speedup vs baseline: 2.2193x; 1.0178x over previous
//
#include <hip/hip_runtime.h>
#include <hip/hip_bf16.h>

typedef __attribute__((ext_vector_type(8))) __bf16 bf16x8;
typedef __attribute__((ext_vector_type(4))) float floatx4;

#define N_NODES   20000
#define N_EDGES   320000
#define IN_DIM    128
#define HID       64
#define HEADS     4
#define NUM_GRAPHS 128
#define N_CLASSES 10

__device__ inline float cvt_load(const void* p, int i, int isb) {
    return isb ? __bfloat162float(((const __hip_bfloat16*)p)[i]) : ((const float*)p)[i];
}

__device__ inline unsigned short bf16bits(float v) {
    return __builtin_bit_cast(unsigned short, __float2bfloat16(v));
}

__device__ inline unsigned pack2(float a, float b) {
    return (unsigned)bf16bits(a) | ((unsigned)bf16bits(b) << 16);
}

__device__ inline floatx4 unpack4(uint2 u) {
    floatx4 f;
    f.x = __uint_as_float(u.x << 16);
    f.y = __uint_as_float(u.x & 0xffff0000u);
    f.z = __uint_as_float(u.y << 16);
    f.w = __uint_as_float(u.y & 0xffff0000u);
    return f;
}

// ---------- init: block 0 = dtype detect; remaining blocks zero cnt and gcnt+pooled ----------
__global__ void init_kernel(const unsigned int* hw, int nwords, int* flag,
                            unsigned int* cnt, int n1, unsigned int* gz, int n2) {
    int b = blockIdx.x;
    if (b == 0) {
        __shared__ int s_bad;
        if (threadIdx.x == 0) s_bad = 0;
        __syncthreads();
        int bad = 0;
        for (int i = threadIdx.x; i < nwords; i += 256) {
            float v = __uint_as_float(hw[i]);
            if (!(fabsf(v) <= 1e20f)) bad = 1;
        }
        if (bad) atomicOr(&s_bad, 1);
        __syncthreads();
        if (threadIdx.x == 0) *flag = s_bad;
    } else {
        int i = (b - 1) * 256 + threadIdx.x;
        if (i < n1) cnt[i] = 0u;
        int j = i - n1;
        if (j >= 0 && j < n2) gz[j] = 0u;
    }
}

// ---------- fused prep: convW [0,195) | convH [195,835) (SKIPPED if bf16) | count [835,2085) ----------
__global__ void prep_kernel(const void* W1, const void* W2, const void* Wc, const void* bc,
                            unsigned short* W1t, unsigned short* W2t, float* Wcf, float* bcf,
                            const void* h, unsigned short* hb,
                            const int* __restrict__ dst, int* __restrict__ cnt,
                            const int* flag) {
    int b = blockIdx.x;
    const int n1 = IN_DIM * HID * HEADS;        // 32768
    const int n2 = HID * HEADS * HID;           // 16384
    const int n3 = HID * N_CLASSES;             // 640
    const int n4 = N_CLASSES;                   // 10
    if (b < 195) {
        int i = b * 256 + threadIdx.x;
        int isb = *flag;
        if (i < n1) {
            int k = i >> 8, n = i & 255;            // W1[k][n]
            W1t[n * 128 + k] = bf16bits(cvt_load(W1, i, isb));
        } else if (i < n1 + n2) {
            int j = i - n1;
            int k = j >> 6, n = j & 63;             // W2[k][n]
            W2t[n * 256 + k] = bf16bits(cvt_load(W2, j, isb));
        } else if (i < n1 + n2 + n3) {
            int j = i - n1 - n2;
            Wcf[j] = cvt_load(Wc, j, isb);
        } else if (i < n1 + n2 + n3 + n4) {
            int j = i - n1 - n2 - n3;
            bcf[j] = cvt_load(bc, j, isb);
        }
    } else if (b < 195 + 640) {
        // convert h -> bf16 ONLY if input is f32; bf16 inputs are consumed in place by gemm1
        int isb = *flag;
        if (!isb) {
            int base = (b - 195) * 4096;
            for (int t = 0; t < 16; ++t) {
                int i = base + t * 256 + threadIdx.x;
                if (i < N_NODES * IN_DIM) hb[i] = bf16bits(cvt_load(h, i, 0));
            }
        }
    } else {
        int e = (b - 835) * 256 + threadIdx.x;
        if (e < N_EDGES) atomicAdd(&cnt[dst[e]], 1);
    }
}

// ---------- scan: 1024 threads, 20 elements/thread serial + ONE block scan ----------
__global__ void scan_kernel(const int* __restrict__ cnt, int* __restrict__ off,
                            int* __restrict__ off_work, int n) {
    const int CH = 20;   // 1024*20 = 20480 >= N_NODES
    __shared__ int wsum[16];
    int tid  = threadIdx.x;
    int lane = tid & 63;
    int w    = tid >> 6;
    int base = tid * CH;
    int local[CH];
    int s = 0;
#pragma unroll
    for (int i = 0; i < CH; ++i) {
        int idx = base + i;
        int v = (idx < n) ? cnt[idx] : 0;
        local[i] = s;          // exclusive within thread
        s += v;
    }
    int x = s;
#pragma unroll
    for (int sh = 1; sh < 64; sh <<= 1) {
        int t = __shfl_up(x, sh);
        if (lane >= sh) x += t;
    }
    if (lane == 63) wsum[w] = x;
    __syncthreads();
    if (w == 0 && lane < 16) {
        int y = wsum[lane];
#pragma unroll
        for (int sh = 1; sh < 16; sh <<= 1) {
            int t = __shfl_up(y, sh);
            if (lane >= sh) y += t;
        }
        wsum[lane] = y;
    }
    __syncthreads();
    int thread_off = ((w > 0) ? wsum[w - 1] : 0) + (x - s);   // exclusive prefix of this thread
#pragma unroll
    for (int i = 0; i < CH; ++i) {
        int idx = base + i;
        if (idx < n) {
            int e = thread_off + local[i];
            off[idx] = e;
            off_work[idx] = e;
        }
    }
    if (tid == 1023) off[n] = thread_off + s;
}

__global__ void fill_kernel(const int* src, const int* dst, int* off_work, int* csr_src, int n) {
    int e = blockIdx.x * blockDim.x + threadIdx.x;
    if (e >= n) return;
    int d = dst[e];
    int pos = atomicAdd(&off_work[d], 1);
    csr_src[pos] = src[e];
}

// ---------- GEMM1 (MFMA): ft1[M,256] = A[M,128] @ W1; A = h_raw (bf16) or h_b (converted) ----------
__global__ __launch_bounds__(256) void gemm1_kernel(const void* __restrict__ h_any,
                                                    const unsigned short* __restrict__ h_b,
                                                    const unsigned short* __restrict__ Bt,
                                                    unsigned short* __restrict__ C, int M,
                                                    const int* flag) {
    const unsigned short* A = (*flag) ? (const unsigned short*)h_any : h_b;
    int wave = threadIdx.x >> 6;
    int lane = threadIdx.x & 63;
    int q = lane >> 4, r = lane & 15;
    int m0 = blockIdx.x * 64;
    int n0 = wave * 64;
    floatx4 acc[4][4] = {};
    bf16x8 bfrag[4][4];
#pragma unroll
    for (int ni = 0; ni < 4; ++ni)
#pragma unroll
        for (int kk = 0; kk < 4; ++kk)
            bfrag[ni][kk] = *(const bf16x8*)(Bt + (n0 + ni * 16 + r) * 128 + kk * 32 + q * 8);
#pragma unroll
    for (int kk = 0; kk < 4; ++kk) {
        bf16x8 afrag[4];
#pragma unroll
        for (int mi = 0; mi < 4; ++mi) {
            int row = m0 + mi * 16 + r;
            bf16x8 a = {};
            if (row < M) a = *(const bf16x8*)(A + row * 128 + kk * 32 + q * 8);
            afrag[mi] = a;
        }
#pragma unroll
        for (int mi = 0; mi < 4; ++mi)
#pragma unroll
            for (int ni = 0; ni < 4; ++ni)
                acc[mi][ni] = __builtin_amdgcn_mfma_f32_16x16x32_bf16(afrag[mi], bfrag[ni][kk], acc[mi][ni], 0, 0, 0);
    }
#pragma unroll
    for (int mi = 0; mi < 4; ++mi)
#pragma unroll
        for (int rr = 0; rr < 4; ++rr) {
            int row = m0 + mi * 16 + q * 4 + rr;
            if (row < M) {
#pragma unroll
                for (int ni = 0; ni < 4; ++ni)
                    C[row * 256 + n0 + ni * 16 + r] = bf16bits(acc[mi][ni][rr]);
            }
        }
}

// ---------- GEMM2 (MFMA, proven): ft2[M,64] = x1[M,256] @ W2 ----------
__global__ __launch_bounds__(256) void gemm2_kernel(const unsigned short* __restrict__ A,
                                                    const unsigned short* __restrict__ Bt,
                                                    unsigned short* __restrict__ C, int M) {
    int wave = threadIdx.x >> 6;
    int lane = threadIdx.x & 63;
    int q = lane >> 4, r = lane & 15;
    int m0 = blockIdx.x * 256 + wave * 64;
    floatx4 acc[4][4] = {};
#pragma unroll
    for (int kk = 0; kk < 8; ++kk) {
        bf16x8 bfrag[4], afrag[4];
#pragma unroll
        for (int ni = 0; ni < 4; ++ni)
            bfrag[ni] = *(const bf16x8*)(Bt + (ni * 16 + r) * 256 + kk * 32 + q * 8);
#pragma unroll
        for (int mi = 0; mi < 4; ++mi) {
            int row = m0 + mi * 16 + r;
            bf16x8 a = {};
            if (row < M) a = *(const bf16x8*)(A + row * 256 + kk * 32 + q * 8);
            afrag[mi] = a;
        }
#pragma unroll
        for (int mi = 0; mi < 4; ++mi)
#pragma unroll
            for (int ni = 0; ni < 4; ++ni)
                acc[mi][ni] = __builtin_amdgcn_mfma_f32_16x16x32_bf16(afrag[mi], bfrag[ni], acc[mi][ni], 0, 0, 0);
    }
#pragma unroll
    for (int mi = 0; mi < 4; ++mi)
#pragma unroll
        for (int rr = 0; rr < 4; ++rr) {
            int row = m0 + mi * 16 + q * 4 + rr;
            if (row < M) {
#pragma unroll
                for (int ni = 0; ni < 4; ++ni)
                    C[row * 64 + ni * 16 + r] = bf16bits(acc[mi][ni][rr]);
            }
        }
}

// ---------- attention H=4: wave = dst, all 4 heads; UNROLL-BY-4 ----------
__global__ __launch_bounds__(256) void attn_h4_kernel(const unsigned short* __restrict__ ft,
                                                      const int* __restrict__ off,
                                                      const int* __restrict__ csr,
                                                      unsigned short* __restrict__ out) {
    int dstv = blockIdx.x * 4 + (threadIdx.x >> 6);
    int lane = threadIdx.x & 63;
    floatx4 hd = unpack4(*(const uint2*)(ft + dstv * 256 + lane * 4));
    int beg = off[dstv], end = off[dstv + 1];
    float l = 0.f;
    floatx4 acc = {0.f, 0.f, 0.f, 0.f};
    int e = beg;
    for (; e + 4 <= end; e += 4) {
        int sn0 = csr[e], sn1 = csr[e + 1], sn2 = csr[e + 2], sn3 = csr[e + 3];
        uint2 r0 = *(const uint2*)(ft + sn0 * 256 + lane * 4);
        uint2 r1 = *(const uint2*)(ft + sn1 * 256 + lane * 4);
        uint2 r2 = *(const uint2*)(ft + sn2 * 256 + lane * 4);
        uint2 r3 = *(const uint2*)(ft + sn3 * 256 + lane * 4);
        floatx4 h0 = unpack4(r0), h1 = unpack4(r1), h2 = unpack4(r2), h3 = unpack4(r3);
        float p0 = h0.x * hd.x + h0.y * hd.y + h0.z * hd.z + h0.w * hd.w;
        float p1 = h1.x * hd.x + h1.y * hd.y + h1.z * hd.z + h1.w * hd.w;
        float p2 = h2.x * hd.x + h2.y * hd.y + h2.z * hd.z + h2.w * hd.w;
        float p3 = h3.x * hd.x + h3.y * hd.y + h3.z * hd.z + h3.w * hd.w;
        p0 += __shfl_xor(p0, 1); p1 += __shfl_xor(p1, 1); p2 += __shfl_xor(p2, 1); p3 += __shfl_xor(p3, 1);
        p0 += __shfl_xor(p0, 2); p1 += __shfl_xor(p1, 2); p2 += __shfl_xor(p2, 2); p3 += __shfl_xor(p3, 2);
        p0 += __shfl_xor(p0, 4); p1 += __shfl_xor(p1, 4); p2 += __shfl_xor(p2, 4); p3 += __shfl_xor(p3, 4);
        p0 += __shfl_xor(p0, 8); p1 += __shfl_xor(p1, 8); p2 += __shfl_xor(p2, 8); p3 += __shfl_xor(p3, 8);
        float w0 = __expf(p0 * 0.125f);
        float w1 = __expf(p1 * 0.125f);
        float w2 = __expf(p2 * 0.125f);
        float w3 = __expf(p3 * 0.125f);
        l += (w0 + w1) + (w2 + w3);
        acc.x += w0 * h0.x + w1 * h1.x + w2 * h2.x + w3 * h3.x;
        acc.y += w0 * h0.y + w1 * h1.y + w2 * h2.y + w3 * h3.y;
        acc.z += w0 * h0.z + w1 * h1.z + w2 * h2.z + w3 * h3.z;
        acc.w += w0 * h0.w + w1 * h1.w + w2 * h2.w + w3 * h3.w;
    }
    for (; e < end; ++e) {
        int sn = csr[e];
        floatx4 hs = unpack4(*(const uint2*)(ft + sn * 256 + lane * 4));
        float p = hs.x * hd.x + hs.y * hd.y + hs.z * hd.z + hs.w * hd.w;
        p += __shfl_xor(p, 1); p += __shfl_xor(p, 2);
        p += __shfl_xor(p, 4); p += __shfl_xor(p, 8);
        float wgt = __expf(p * 0.125f);
        l += wgt;
        acc.x += wgt * hs.x; acc.y += wgt * hs.y;
        acc.z += wgt * hs.z; acc.w += wgt * hs.w;
    }
    float inv = (l > 0.f) ? 1.f / l : 0.f;
    uint2 o;
    o.x = pack2(fmaxf(acc.x * inv, 0.f), fmaxf(acc.y * inv, 0.f));
    o.y = pack2(fmaxf(acc.z * inv, 0.f), fmaxf(acc.w * inv, 0.f));
    *(uint2*)(out + dstv * 256 + lane * 4) = o;
}

// ---------- attention H=1: wave = dst, 4 edge-groups x 16 lanes; UNROLL-BY-2 ----------
__global__ __launch_bounds__(256) void attn_h1_kernel(const unsigned short* __restrict__ ft,
                                                      const int* __restrict__ off,
                                                      const int* __restrict__ csr,
                                                      float* __restrict__ out) {
    int dstv = blockIdx.x * 4 + (threadIdx.x >> 6);
    int lane = threadIdx.x & 63;
    int g = lane >> 4, s = lane & 15;
    int hbase = s * 4;
    floatx4 hd = unpack4(*(const uint2*)(ft + dstv * 64 + hbase));
    int beg = off[dstv], end = off[dstv + 1];
    float l = 0.f;
    floatx4 acc = {0.f, 0.f, 0.f, 0.f};
    int e0 = beg;
    for (; e0 + 8 <= end; e0 += 8) {      // both edges unmasked
        int ea = e0 + g, eb = e0 + 4 + g;
        int sa = csr[ea], sb = csr[eb];
        uint2 ra = *(const uint2*)(ft + sa * 64 + hbase);
        uint2 rb = *(const uint2*)(ft + sb * 64 + hbase);
        floatx4 ha = unpack4(ra), hb = unpack4(rb);
        float pa = ha.x * hd.x + ha.y * hd.y + ha.z * hd.z + ha.w * hd.w;
        float pb = hb.x * hd.x + hb.y * hd.y + hb.z * hd.z + hb.w * hd.w;
        pa += __shfl_xor(pa, 1); pb += __shfl_xor(pb, 1);
        pa += __shfl_xor(pa, 2); pb += __shfl_xor(pb, 2);
        pa += __shfl_xor(pa, 4); pb += __shfl_xor(pb, 4);
        pa += __shfl_xor(pa, 8); pb += __shfl_xor(pb, 8);
        float wa = __expf(pa * 0.125f);
        float wb = __expf(pb * 0.125f);
        l += wa + wb;
        acc.x += wa * ha.x + wb * hb.x;
        acc.y += wa * ha.y + wb * hb.y;
        acc.z += wa * ha.z + wb * hb.z;
        acc.w += wa * ha.w + wb * hb.w;
    }
    for (; e0 < end; e0 += 4) {
        int e = e0 + g;
        bool valid = (e < end);
        int sn = valid ? csr[e] : 0;
        floatx4 hs = unpack4(*(const uint2*)(ft + sn * 64 + hbase));
        float p = hs.x * hd.x + hs.y * hd.y + hs.z * hd.z + hs.w * hd.w;
        p += __shfl_xor(p, 1); p += __shfl_xor(p, 2);
        p += __shfl_xor(p, 4); p += __shfl_xor(p, 8);
        float wgt = valid ? __expf(p * 0.125f) : 0.f;
        l += wgt;
        acc.x += wgt * hs.x; acc.y += wgt * hs.y;
        acc.z += wgt * hs.z; acc.w += wgt * hs.w;
    }
    l += __shfl_xor(l, 16); l += __shfl_xor(l, 32);
    acc.x += __shfl_xor(acc.x, 16); acc.x += __shfl_xor(acc.x, 32);
    acc.y += __shfl_xor(acc.y, 16); acc.y += __shfl_xor(acc.y, 32);
    acc.z += __shfl_xor(acc.z, 16); acc.z += __shfl_xor(acc.z, 32);
    acc.w += __shfl_xor(acc.w, 16); acc.w += __shfl_xor(acc.w, 32);
    float inv = (l > 0.f) ? 1.f / l : 0.f;
    if (g == 0) {
        floatx4 o = {fmaxf(acc.x * inv, 0.f), fmaxf(acc.y * inv, 0.f),
                     fmaxf(acc.z * inv, 0.f), fmaxf(acc.w * inv, 0.f)};
        *(floatx4*)(out + dstv * 64 + hbase) = o;
    }
}

// ---------- pooling (proven) ----------
__global__ void pool_kernel(const float* __restrict__ x, const int* __restrict__ gid,
                            float* pooled, int* gcnt, int n_nodes) {
    int t = blockIdx.x * blockDim.x + threadIdx.x;
    int d = t & 63;
    int n0 = (t >> 6) * 8;
    if (n0 >= n_nodes) return;
    float accv = 0.f;
    int cnt_l = 0;
    int curg = gid[n0];
    for (int i = 0; i < 8 && n0 + i < n_nodes; ++i) {
        int g = gid[n0 + i];
        if (g != curg) {
            atomicAdd(&pooled[curg * 64 + d], accv);
            if (d == 0) atomicAdd(&gcnt[curg], cnt_l);
            accv = 0.f; cnt_l = 0; curg = g;
        }
        accv += x[(n0 + i) * 64 + d];
        cnt_l++;
    }
    atomicAdd(&pooled[curg * 64 + d], accv);
    if (d == 0) atomicAdd(&gcnt[curg], cnt_l);
}

// ---------- classifier (proven) ----------
__global__ void classifier_kernel(const float* __restrict__ pooled, const int* __restrict__ gcnt,
                                  const float* __restrict__ Wc, const float* __restrict__ bc,
                                  void* out, const int* flag) {
    int g = blockIdx.x;
    int d = threadIdx.x;
    float c = (float)max(gcnt[g], 1);
    float val = pooled[g * 64 + d] / c;
    for (int cls = 0; cls < N_CLASSES; ++cls) {
        float p = val * Wc[d * N_CLASSES + cls];
#pragma unroll
        for (int o = 1; o < 64; o <<= 1) p += __shfl_xor(p, o);
        if (d == 0) {
            float r = p + bc[cls];
            if (*flag) ((__hip_bfloat16*)out)[g * N_CLASSES + cls] = __float2bfloat16(r);
            else       ((float*)out)[g * N_CLASSES + cls] = r;
        }
    }
}

static inline size_t align256(size_t x) { return (x + 255) & ~size_t(255); }

extern "C" void kernel_launch(void* const* d_in, const int* in_sizes, int n_in,
                              void* d_out, int out_size, void* d_ws, size_t ws_size,
                              hipStream_t stream) {
    const void* h_raw  = d_in[0];
    const int*  src    = (const int*)d_in[1];
    const int*  dst    = (const int*)d_in[2];
    const int*  gid    = (const int*)d_in[3];
    const void* W1_raw = d_in[4];
    const void* W2_raw = d_in[5];
    const void* Wc_raw = d_in[6];
    const void* bc_raw = d_in[7];

    // ---- workspace layout ----
    char* w = (char*)d_ws;
    int*  flag     = (int*)w;                      w += 256;
    int*  cnt      = (int*)w;                      w += align256(N_NODES * 4);
    int*  off      = (int*)w;                      w += align256((N_NODES + 1) * 4);
    int*  off_work = (int*)w;                      w += align256(N_NODES * 4);
    int*  csr_src  = (int*)w;                      w += align256(N_EDGES * 4);
    int*  gcnt     = (int*)w;                      w += 512;
    float* pooled  = (float*)w;                    w += NUM_GRAPHS * HID * 4;
    unsigned short* W1t = (unsigned short*)w;      w += align256(256 * 128 * 2);
    unsigned short* W2t = (unsigned short*)w;      w += align256(64 * 256 * 2);
    float* Wcf     = (float*)w;                    w += align256(HID * N_CLASSES * 4);
    float* bcf     = (float*)w;                    w += 256;
    unsigned short* h_b  = (unsigned short*)w;     w += align256((size_t)N_NODES * IN_DIM * 2);
    unsigned short* ft1  = (unsigned short*)w;     w += align256((size_t)N_NODES * 256 * 2);
    unsigned short* x1   = (unsigned short*)w;     w += align256((size_t)N_NODES * 256 * 2);
    unsigned short* ft2  = (unsigned short*)w;     w += align256((size_t)N_NODES * HID * 2);
    float* x2      = (float*)w;                    w += align256((size_t)N_NODES * HID * 4);

    // 1) init: detect (block 0) + zero cnt/gcnt/pooled
    {
        int nz = N_NODES + (128 + NUM_GRAPHS * HID);
        hipLaunchKernelGGL(init_kernel, dim3(1 + (nz + 255) / 256), dim3(256), 0, stream,
                           (const unsigned int*)h_raw, 4096, flag,
                           (unsigned int*)cnt, N_NODES,
                           (unsigned int*)gcnt, 128 + NUM_GRAPHS * HID);
    }

    // 2) fused prep: convW (195) + convH-if-f32 (640) + count (1250)
    hipLaunchKernelGGL(prep_kernel, dim3(195 + 640 + 1250), dim3(256), 0, stream,
                       W1_raw, W2_raw, Wc_raw, bc_raw, W1t, W2t, Wcf, bcf,
                       h_raw, h_b, dst, cnt, flag);

    // 3) CSR scan + fill
    hipLaunchKernelGGL(scan_kernel, dim3(1), dim3(1024), 0, stream, cnt, off, off_work, N_NODES);
    hipLaunchKernelGGL(fill_kernel, dim3((N_EDGES + 255) / 256), dim3(256), 0, stream,
                       src, dst, off_work, csr_src, N_EDGES);

    // 4) layer 1 GEMM (MFMA); A = h_raw directly when bf16
    hipLaunchKernelGGL(gemm1_kernel, dim3((N_NODES + 63) / 64), dim3(256), 0, stream,
                       h_raw, h_b, W1t, ft1, N_NODES, flag);
    // 5) attention layer 1 -> x1 (bf16)
    hipLaunchKernelGGL(attn_h4_kernel, dim3(N_NODES / 4), dim3(256), 0, stream,
                       ft1, off, csr_src, x1);

    // 6) layer 2 GEMM (MFMA)
    hipLaunchKernelGGL(gemm2_kernel, dim3((N_NODES + 255) / 256), dim3(256), 0, stream,
                       x1, W2t, ft2, N_NODES);
    // 7) attention layer 2 -> x2 (f32)
    hipLaunchKernelGGL(attn_h1_kernel, dim3(N_NODES / 4), dim3(256), 0, stream,
                       ft2, off, csr_src, x2);

    // 8) mean pool
    {
        int threads = (N_NODES / 8) * 64;
        hipLaunchKernelGGL(pool_kernel, dim3((threads + 255) / 256), dim3(256), 0, stream,
                           x2, gid, pooled, gcnt, N_NODES);
    }

    // 9) classifier -> d_out
    hipLaunchKernelGGL(classifier_kernel, dim3(NUM_GRAPHS), dim3(64), 0, stream,
                       pooled, gcnt, Wcf, bcf, d_out, flag);
}